// Round 7
// baseline (11908.431 us; speedup 1.0000x reference)
//
#include <hip/hip_runtime.h>
#include <hip/hip_fp16.h>

#define NPIX   512
#define NDET   768
#define NSAMP  768
#define NVIEW  360
#define NBATCH 8

typedef float v2f __attribute__((ext_vector_type(2)));

#if defined(__has_builtin)
#if __has_builtin(__builtin_amdgcn_cvt_pk_f32_fp8) && __has_builtin(__builtin_amdgcn_cvt_pk_fp8_f32)
#define HAVE_FP8_CVT 1
#endif
#endif

// ---------------------------------------------------------------------------
// Repack image [8,512,512] fp32 -> fp8(e4m3) x-pair-dup [512*512] of 16B:
//   word k (k=0..3) bytes: [b2k@x, b2k@x+1, b2k+1@x, b2k+1@x+1]  (x+1 clamped)
// One dwordx4 gather = one corner-ROW (both x-corners, all 8 batches).
// Footprint 4 MB -> L2-resident (R4 lesson: 8 MB thrashes).
// ---------------------------------------------------------------------------
__global__ __launch_bounds__(256) void repack_kernel(
    const float* __restrict__ image,    // [8, 512, 512]
    int4* __restrict__ packed)          // [512*512]
{
    const int idx = blockIdx.x * blockDim.x + threadIdx.x;  // (y<<9)|x
    if (idx >= NPIX * NPIX) return;
    const int x  = idx & (NPIX - 1);
    const int x1 = min(x + 1, NPIX - 1);
    const int base = idx - x;
    int w[4];
#pragma unroll
    for (int k = 0; k < 4; ++k) {
        const float* imgA = image + (size_t)(2 * k)     * (NPIX * NPIX) + base;
        const float* imgB = image + (size_t)(2 * k + 1) * (NPIX * NPIX) + base;
#ifdef HAVE_FP8_CVT
        int r = 0;
        r = __builtin_amdgcn_cvt_pk_fp8_f32(imgA[x], imgA[x1], r, false); // bytes 0,1
        r = __builtin_amdgcn_cvt_pk_fp8_f32(imgB[x], imgB[x1], r, true);  // bytes 2,3
        w[k] = r;
#else
        w[k] = 0;
#endif
    }
    packed[idx] = make_int4(w[0], w[1], w[2], w[3]);
}

// Accumulate one corner-row: 16 fp8 (8 batches x {x0,x1}) with weight pair wv.
__device__ __forceinline__ void acc_row(const int4 q, const v2f wv, v2f accp[NBATCH]) {
#ifdef HAVE_FP8_CVT
    const int w0 = q.x, w1 = q.y, w2 = q.z, w3 = q.w;
    accp[0] += ((v2f)__builtin_amdgcn_cvt_pk_f32_fp8(w0, false)) * wv;
    accp[1] += ((v2f)__builtin_amdgcn_cvt_pk_f32_fp8(w0, true))  * wv;
    accp[2] += ((v2f)__builtin_amdgcn_cvt_pk_f32_fp8(w1, false)) * wv;
    accp[3] += ((v2f)__builtin_amdgcn_cvt_pk_f32_fp8(w1, true))  * wv;
    accp[4] += ((v2f)__builtin_amdgcn_cvt_pk_f32_fp8(w2, false)) * wv;
    accp[5] += ((v2f)__builtin_amdgcn_cvt_pk_f32_fp8(w2, true))  * wv;
    accp[6] += ((v2f)__builtin_amdgcn_cvt_pk_f32_fp8(w3, false)) * wv;
    accp[7] += ((v2f)__builtin_amdgcn_cvt_pk_f32_fp8(w3, true))  * wv;
#endif
}

// ---------------------------------------------------------------------------
// Main projector. Wave = 16 detectors x 4 sample-offsets (R6 patch locality).
// Per sample: TWO dwordx4 gathers (rows y0,y1); fp8 decode via v_cvt_pk_f32_fp8;
// packed v_pk_fma_f32 accumulate. shfl_xor reduce over soff; plain stores.
// ---------------------------------------------------------------------------
__global__ __launch_bounds__(256) void projector_kernel(
    const int4* __restrict__ pk,        // [512*512] x-pair-dup fp8
    const float* __restrict__ views,    // [360]
    float* __restrict__ out)            // [8, 360, 768]
{
    const int lane    = threadIdx.x & 63;
    const int wave    = threadIdx.x >> 6;        // 0..3
    const int detlane = lane & 15;
    const int soff    = lane >> 4;               // 0..3
    const int d = blockIdx.x * 64 + wave * 16 + detlane;
    const int v = blockIdx.y;

    const float PIX   = 0.7433f;
    const float ISO   = 595.0f;
    const float SDD_  = 595.0f + 490.6f;
    const float DGAM  = 1.2858f / SDD_;
    const float FOV   = 512.0f * 0.7433f * 0.70710678f;
    const float T0    = ISO - FOV;
    const float DT    = 2.0f * FOV / (float)NSAMP;

    const float beta  = views[v];
    const float gamma = ((float)d - 0.5f * (float)(NDET - 1)) * DGAM;
    const float sx = ISO * cosf(beta);
    const float sy = ISO * sinf(beta);
    const float ang = beta + 3.14159265358979f + gamma;
    const float gx = cosf(ang) / PIX;
    const float gy = sinf(ang) / PIX;
    const float cx = sx / PIX + 0.5f * (float)(NPIX - 1);
    const float cy = sy / PIX + 0.5f * (float)(NPIX - 1);

    // ---- clip sample range to padded image box (pad 3 px; outside = 0) ----
    const float PLO = -3.0f, PHI = (float)NPIX + 2.0f;
    float lo = T0 + 0.5f * DT;
    float hi = T0 + ((float)NSAMP - 0.5f) * DT;
    if (fabsf(gx) > 1e-8f) {
        float ta = (PLO - cx) / gx, tb = (PHI - cx) / gx;
        lo = fmaxf(lo, fminf(ta, tb));
        hi = fminf(hi, fmaxf(ta, tb));
    } else if (cx < PLO || cx > PHI) {
        hi = lo - 1.0f;
    }
    if (fabsf(gy) > 1e-8f) {
        float ta = (PLO - cy) / gy, tb = (PHI - cy) / gy;
        lo = fmaxf(lo, fminf(ta, tb));
        hi = fminf(hi, fmaxf(ta, tb));
    } else if (cy < PLO || cy > PHI) {
        hi = lo - 1.0f;
    }

    int s_begin = 0, s_end = 0;
    if (hi >= lo) {
        s_begin = max(0, (int)floorf((lo - T0) / DT - 0.5f));
        s_end   = min(NSAMP, (int)ceilf((hi - T0) / DT - 0.5f) + 1);
    }

    // ---- interior range: strictly inside [0.01, 510.99]^2 (no clamping) ---
    const float XLO = 0.01f, XHI = 510.99f;
    float ilo = lo, ihi = hi;
    if (fabsf(gx) > 1e-8f) {
        float ta = (XLO - cx) / gx, tb = (XHI - cx) / gx;
        ilo = fmaxf(ilo, fminf(ta, tb));
        ihi = fminf(ihi, fmaxf(ta, tb));
    } else if (cx < XLO || cx > XHI) {
        ihi = ilo - 1.0f;
    }
    if (fabsf(gy) > 1e-8f) {
        float ta = (XLO - cy) / gy, tb = (XHI - cy) / gy;
        ilo = fmaxf(ilo, fminf(ta, tb));
        ihi = fminf(ihi, fmaxf(ta, tb));
    } else if (cy < XLO || cy > XHI) {
        ihi = ilo - 1.0f;
    }

    int ib = s_begin, ie = s_begin;
    if (ihi >= ilo) {
        ib = max(s_begin, (int)ceilf ((ilo - T0) / DT - 0.5f));
        ie = min(s_end,   (int)floorf((ihi - T0) / DT - 0.5f) + 1);
        if (ie < ib) { ib = s_begin; ie = s_begin; }
    }

    const float fxs = gx * DT;
    const float fys = gy * DT;
    const float fx0 = fmaf(gx, T0 + 0.5f * DT, cx);
    const float fy0 = fmaf(gy, T0 + 0.5f * DT, cy);

    v2f accp[NBATCH];
#pragma unroll
    for (int b = 0; b < NBATCH; ++b) accp[b] = (v2f)(0.0f);

    int s = s_begin + soff;          // this thread's samples: step 4

    // ---------------- border loop 1: s < ib --------------------------------
    for (; s < ib; s += 4) {
        const float sf = (float)s;
        const float fx = fmaf(fxs, sf, fx0);
        const float fy = fmaf(fys, sf, fy0);
        const float x0f = floorf(fx), y0f = floorf(fy);
        const float wx = fx - x0f, wy = fy - y0f;
        const int ix = (int)x0f, iy = (int)y0f;
        const float ax = 1.0f - wx, ay = 1.0f - wy;
        const bool vx0 = (unsigned)ix       < (unsigned)NPIX;
        const bool vx1 = (unsigned)(ix + 1) < (unsigned)NPIX;
        const bool vy0 = (unsigned)iy       < (unsigned)NPIX;
        const bool vy1 = (unsigned)(iy + 1) < (unsigned)NPIX;
        float w00 = (vx0 && vy0) ? ax * ay : 0.0f;
        float w01 = (vx1 && vy0) ? wx * ay : 0.0f;
        float w10 = (vx0 && vy1) ? ax * wy : 0.0f;
        float w11 = (vx1 && vy1) ? wx * wy : 0.0f;
        // pair slot holds (v[xc0], v[xc0+1]); if ix<0 the valid x=0 value is
        // in slot 0 -> shift weights left (R4 trick)
        const bool xneg = (ix < 0);
        const v2f wv0 = { xneg ? w01 : w00, xneg ? 0.0f : w01 };
        const v2f wv1 = { xneg ? w11 : w10, xneg ? 0.0f : w11 };
        const int xc0 = min(max(ix,     0), NPIX - 1);
        const int yc0 = min(max(iy,     0), NPIX - 1);
        const int yc1 = min(max(iy + 1, 0), NPIX - 1);
        acc_row(pk[(yc0 << 9) + xc0], wv0, accp);
        acc_row(pk[(yc1 << 9) + xc0], wv1, accp);
    }

    // ---------------- interior loop: s < ie (no clamps/selects) ------------
    for (; s < ie; s += 4) {
        const float sf = (float)s;
        const float fx = fmaf(fxs, sf, fx0);
        const float fy = fmaf(fys, sf, fy0);
        const float x0f = floorf(fx), y0f = floorf(fy);
        const float wx = fx - x0f, wy = fy - y0f;
        const int ix = (int)x0f, iy = (int)y0f;
        const float ax = 1.0f - wx, ay = 1.0f - wy;
        const v2f axwx = { ax, wx };
        const v2f wv0 = axwx * ay;       // (w00, w01)
        const v2f wv1 = axwx * wy;       // (w10, w11)
        const int p0 = (iy << 9) + ix;
        acc_row(pk[p0],        wv0, accp);
        acc_row(pk[p0 + NPIX], wv1, accp);
    }

    // ---------------- border loop 2: s < s_end -----------------------------
    for (; s < s_end; s += 4) {
        const float sf = (float)s;
        const float fx = fmaf(fxs, sf, fx0);
        const float fy = fmaf(fys, sf, fy0);
        const float x0f = floorf(fx), y0f = floorf(fy);
        const float wx = fx - x0f, wy = fy - y0f;
        const int ix = (int)x0f, iy = (int)y0f;
        const float ax = 1.0f - wx, ay = 1.0f - wy;
        const bool vx0 = (unsigned)ix       < (unsigned)NPIX;
        const bool vx1 = (unsigned)(ix + 1) < (unsigned)NPIX;
        const bool vy0 = (unsigned)iy       < (unsigned)NPIX;
        const bool vy1 = (unsigned)(iy + 1) < (unsigned)NPIX;
        float w00 = (vx0 && vy0) ? ax * ay : 0.0f;
        float w01 = (vx1 && vy0) ? wx * ay : 0.0f;
        float w10 = (vx0 && vy1) ? ax * wy : 0.0f;
        float w11 = (vx1 && vy1) ? wx * wy : 0.0f;
        const bool xneg = (ix < 0);
        const v2f wv0 = { xneg ? w01 : w00, xneg ? 0.0f : w01 };
        const v2f wv1 = { xneg ? w11 : w10, xneg ? 0.0f : w11 };
        const int xc0 = min(max(ix,     0), NPIX - 1);
        const int yc0 = min(max(iy,     0), NPIX - 1);
        const int yc1 = min(max(iy + 1, 0), NPIX - 1);
        acc_row(pk[(yc0 << 9) + xc0], wv0, accp);
        acc_row(pk[(yc1 << 9) + xc0], wv1, accp);
    }

    // ---- fold x0/x1 halves, reduce the 4 soff partials, store -------------
    float acc[NBATCH];
#pragma unroll
    for (int b = 0; b < NBATCH; ++b) {
        acc[b] = accp[b].x + accp[b].y;
        acc[b] += __shfl_xor(acc[b], 16, 64);
        acc[b] += __shfl_xor(acc[b], 32, 64);
    }

    if (soff == 0) {
#pragma unroll
        for (int b = 0; b < NBATCH; ++b)
            out[((size_t)b * NVIEW + v) * NDET + d] = acc[b] * DT;
    }
}

// ---------------------------------------------------------------------------
// Fallback (original layout, fp32 scalar loads) — also used if fp8 cvt
// builtins are unavailable or ws too small.
// ---------------------------------------------------------------------------
__global__ __launch_bounds__(256) void projector_kernel_fallback(
    const float* __restrict__ image, const float* __restrict__ views,
    float* __restrict__ out)
{
    const int d = blockIdx.x * blockDim.x + threadIdx.x;
    const int v = blockIdx.y;
    if (d >= NDET) return;

    const float PIX = 0.7433f, ISO = 595.0f;
    const float SDD_ = 595.0f + 490.6f;
    const float DGAM = 1.2858f / SDD_;
    const float FOV  = 512.0f * 0.7433f * 0.70710678f;
    const float T0   = ISO - FOV;
    const float DT   = 2.0f * FOV / (float)NSAMP;

    const float beta  = views[v];
    const float gamma = ((float)d - 0.5f * (float)(NDET - 1)) * DGAM;
    const float sx = ISO * cosf(beta), sy = ISO * sinf(beta);
    const float ang = beta + 3.14159265358979f + gamma;
    const float gx = cosf(ang) / PIX, gy = sinf(ang) / PIX;
    const float cx = sx / PIX + 0.5f * (float)(NPIX - 1);
    const float cy = sy / PIX + 0.5f * (float)(NPIX - 1);

    float acc[NBATCH];
#pragma unroll
    for (int b = 0; b < NBATCH; ++b) acc[b] = 0.0f;

    for (int s = 0; s < NSAMP; ++s) {
        const float t  = fmaf((float)s + 0.5f, DT, T0);
        const float fx = fmaf(gx, t, cx);
        const float fy = fmaf(gy, t, cy);
        const float x0f = floorf(fx), y0f = floorf(fy);
        const float wx = fx - x0f, wy = fy - y0f;
        const int ix = (int)x0f, iy = (int)y0f;
        const float ax = 1.0f - wx, ay = 1.0f - wy;
        const bool vx0 = (unsigned)ix < (unsigned)NPIX;
        const bool vx1 = (unsigned)(ix + 1) < (unsigned)NPIX;
        const bool vy0 = (unsigned)iy < (unsigned)NPIX;
        const bool vy1 = (unsigned)(iy + 1) < (unsigned)NPIX;
        const float w00 = (vx0 && vy0) ? ax * ay : 0.0f;
        const float w01 = (vx1 && vy0) ? wx * ay : 0.0f;
        const float w10 = (vx0 && vy1) ? ax * wy : 0.0f;
        const float w11 = (vx1 && vy1) ? wx * wy : 0.0f;
        const int xc0 = min(max(ix, 0), NPIX - 1);
        const int xc1 = min(max(ix + 1, 0), NPIX - 1);
        const int yc0 = min(max(iy, 0), NPIX - 1);
        const int yc1 = min(max(iy + 1, 0), NPIX - 1);
        const int i00 = (yc0 << 9) + xc0, i01 = (yc0 << 9) + xc1;
        const int i10 = (yc1 << 9) + xc0, i11 = (yc1 << 9) + xc1;
#pragma unroll
        for (int b = 0; b < NBATCH; ++b) {
            const float* img = image + (size_t)b * (NPIX * NPIX);
            acc[b] = fmaf(w00, img[i00], fmaf(w01, img[i01],
                     fmaf(w10, img[i10], fmaf(w11, img[i11], acc[b]))));
        }
    }
#pragma unroll
    for (int b = 0; b < NBATCH; ++b)
        out[((size_t)b * NVIEW + v) * NDET + d] = acc[b] * DT;
}

extern "C" void kernel_launch(void* const* d_in, const int* in_sizes, int n_in,
                              void* d_out, int out_size, void* d_ws, size_t ws_size,
                              hipStream_t stream) {
    const float* image = (const float*)d_in[0];
    const float* views = (const float*)d_in[1];
    float* out = (float*)d_out;

    const size_t packed_bytes = (size_t)NPIX * NPIX * sizeof(int4);

#ifdef HAVE_FP8_CVT
    const bool use_fp8 = (ws_size >= packed_bytes && d_ws != nullptr);
#else
    const bool use_fp8 = false;
#endif

    if (use_fp8) {
        int4* packed = (int4*)d_ws;
        repack_kernel<<<dim3((NPIX * NPIX) / 256), dim3(256), 0, stream>>>(image, packed);
        projector_kernel<<<dim3(NDET / 64, NVIEW), dim3(256), 0, stream>>>(
            packed, views, out);
    } else {
        projector_kernel_fallback<<<dim3(NDET / 256, NVIEW), dim3(256), 0, stream>>>(image, views, out);
    }
}

// Round 8
// 332.886 us; speedup vs baseline: 35.7733x; 35.7733x over previous
//
#include <hip/hip_runtime.h>
#include <hip/hip_fp16.h>

#define NPIX   512
#define NDET   768
#define NSAMP  768
#define NVIEW  360
#define NBATCH 8

typedef float v2f __attribute__((ext_vector_type(2)));

// ---------------------------------------------------------------------------
// Repack image [8,512,512] fp32 -> fp8(e4m3) x-pair-dup [512*512] of 16B:
//   word k (k=0..3) bytes: [b2k@x, b2k@x+1, b2k+1@x, b2k+1@x+1]  (x+1 clamped)
// One dwordx4 gather = one corner-ROW (both x-corners, all 8 batches).
// Footprint 4 MB -> L2-resident (R4 lesson: 8 MB thrashes).
// NOTE: __builtin_amdgcn_cvt_* used unconditionally in device code — do NOT
// gate on __has_builtin: it is false in the HOST pass and (R7 lesson) any
// host-visible macro derived from it silently disables the fast path.
// ---------------------------------------------------------------------------
__global__ __launch_bounds__(256) void repack_kernel(
    const float* __restrict__ image,    // [8, 512, 512]
    int4* __restrict__ packed)          // [512*512]
{
    const int idx = blockIdx.x * blockDim.x + threadIdx.x;  // (y<<9)|x
    if (idx >= NPIX * NPIX) return;
    const int x  = idx & (NPIX - 1);
    const int x1 = min(x + 1, NPIX - 1);
    const int base = idx - x;
    int w[4];
#pragma unroll
    for (int k = 0; k < 4; ++k) {
        const float* imgA = image + (size_t)(2 * k)     * (NPIX * NPIX) + base;
        const float* imgB = image + (size_t)(2 * k + 1) * (NPIX * NPIX) + base;
        int r = 0;
        r = __builtin_amdgcn_cvt_pk_fp8_f32(imgA[x], imgA[x1], r, false); // bytes 0,1
        r = __builtin_amdgcn_cvt_pk_fp8_f32(imgB[x], imgB[x1], r, true);  // bytes 2,3
        w[k] = r;
    }
    packed[idx] = make_int4(w[0], w[1], w[2], w[3]);
}

// Accumulate one corner-row: 16 fp8 (8 batches x {x0,x1}) with weight pair wv.
__device__ __forceinline__ void acc_row(const int4 q, const v2f wv, v2f accp[NBATCH]) {
    accp[0] += ((v2f)__builtin_amdgcn_cvt_pk_f32_fp8(q.x, false)) * wv;
    accp[1] += ((v2f)__builtin_amdgcn_cvt_pk_f32_fp8(q.x, true))  * wv;
    accp[2] += ((v2f)__builtin_amdgcn_cvt_pk_f32_fp8(q.y, false)) * wv;
    accp[3] += ((v2f)__builtin_amdgcn_cvt_pk_f32_fp8(q.y, true))  * wv;
    accp[4] += ((v2f)__builtin_amdgcn_cvt_pk_f32_fp8(q.z, false)) * wv;
    accp[5] += ((v2f)__builtin_amdgcn_cvt_pk_f32_fp8(q.z, true))  * wv;
    accp[6] += ((v2f)__builtin_amdgcn_cvt_pk_f32_fp8(q.w, false)) * wv;
    accp[7] += ((v2f)__builtin_amdgcn_cvt_pk_f32_fp8(q.w, true))  * wv;
}

// ---------------------------------------------------------------------------
// Main projector. Wave = 16 detectors x 4 sample-offsets (R6 patch locality).
// Per sample: TWO dwordx4 gathers (rows y0,y1); fp8 decode via v_cvt_pk_f32_fp8;
// packed v_pk_fma_f32 accumulate. shfl_xor reduce over soff; plain stores.
// ---------------------------------------------------------------------------
__global__ __launch_bounds__(256) void projector_kernel(
    const int4* __restrict__ pk,        // [512*512] x-pair-dup fp8
    const float* __restrict__ views,    // [360]
    float* __restrict__ out)            // [8, 360, 768]
{
    const int lane    = threadIdx.x & 63;
    const int wave    = threadIdx.x >> 6;        // 0..3
    const int detlane = lane & 15;
    const int soff    = lane >> 4;               // 0..3
    const int d = blockIdx.x * 64 + wave * 16 + detlane;
    const int v = blockIdx.y;

    const float PIX   = 0.7433f;
    const float ISO   = 595.0f;
    const float SDD_  = 595.0f + 490.6f;
    const float DGAM  = 1.2858f / SDD_;
    const float FOV   = 512.0f * 0.7433f * 0.70710678f;
    const float T0    = ISO - FOV;
    const float DT    = 2.0f * FOV / (float)NSAMP;

    const float beta  = views[v];
    const float gamma = ((float)d - 0.5f * (float)(NDET - 1)) * DGAM;
    const float sx = ISO * cosf(beta);
    const float sy = ISO * sinf(beta);
    const float ang = beta + 3.14159265358979f + gamma;
    const float gx = cosf(ang) / PIX;
    const float gy = sinf(ang) / PIX;
    const float cx = sx / PIX + 0.5f * (float)(NPIX - 1);
    const float cy = sy / PIX + 0.5f * (float)(NPIX - 1);

    // ---- clip sample range to padded image box (pad 3 px; outside = 0) ----
    const float PLO = -3.0f, PHI = (float)NPIX + 2.0f;
    float lo = T0 + 0.5f * DT;
    float hi = T0 + ((float)NSAMP - 0.5f) * DT;
    if (fabsf(gx) > 1e-8f) {
        float ta = (PLO - cx) / gx, tb = (PHI - cx) / gx;
        lo = fmaxf(lo, fminf(ta, tb));
        hi = fminf(hi, fmaxf(ta, tb));
    } else if (cx < PLO || cx > PHI) {
        hi = lo - 1.0f;
    }
    if (fabsf(gy) > 1e-8f) {
        float ta = (PLO - cy) / gy, tb = (PHI - cy) / gy;
        lo = fmaxf(lo, fminf(ta, tb));
        hi = fminf(hi, fmaxf(ta, tb));
    } else if (cy < PLO || cy > PHI) {
        hi = lo - 1.0f;
    }

    int s_begin = 0, s_end = 0;
    if (hi >= lo) {
        s_begin = max(0, (int)floorf((lo - T0) / DT - 0.5f));
        s_end   = min(NSAMP, (int)ceilf((hi - T0) / DT - 0.5f) + 1);
    }

    // ---- interior range: strictly inside [0.01, 510.99]^2 (no clamping) ---
    const float XLO = 0.01f, XHI = 510.99f;
    float ilo = lo, ihi = hi;
    if (fabsf(gx) > 1e-8f) {
        float ta = (XLO - cx) / gx, tb = (XHI - cx) / gx;
        ilo = fmaxf(ilo, fminf(ta, tb));
        ihi = fminf(ihi, fmaxf(ta, tb));
    } else if (cx < XLO || cx > XHI) {
        ihi = ilo - 1.0f;
    }
    if (fabsf(gy) > 1e-8f) {
        float ta = (XLO - cy) / gy, tb = (XHI - cy) / gy;
        ilo = fmaxf(ilo, fminf(ta, tb));
        ihi = fminf(ihi, fmaxf(ta, tb));
    } else if (cy < XLO || cy > XHI) {
        ihi = ilo - 1.0f;
    }

    int ib = s_begin, ie = s_begin;
    if (ihi >= ilo) {
        ib = max(s_begin, (int)ceilf ((ilo - T0) / DT - 0.5f));
        ie = min(s_end,   (int)floorf((ihi - T0) / DT - 0.5f) + 1);
        if (ie < ib) { ib = s_begin; ie = s_begin; }
    }

    const float fxs = gx * DT;
    const float fys = gy * DT;
    const float fx0 = fmaf(gx, T0 + 0.5f * DT, cx);
    const float fy0 = fmaf(gy, T0 + 0.5f * DT, cy);

    v2f accp[NBATCH];
#pragma unroll
    for (int b = 0; b < NBATCH; ++b) accp[b] = (v2f)(0.0f);

    int s = s_begin + soff;          // this thread's samples: step 4

    // ---------------- border loop 1: s < ib --------------------------------
    for (; s < ib; s += 4) {
        const float sf = (float)s;
        const float fx = fmaf(fxs, sf, fx0);
        const float fy = fmaf(fys, sf, fy0);
        const float x0f = floorf(fx), y0f = floorf(fy);
        const float wx = fx - x0f, wy = fy - y0f;
        const int ix = (int)x0f, iy = (int)y0f;
        const float ax = 1.0f - wx, ay = 1.0f - wy;
        const bool vx0 = (unsigned)ix       < (unsigned)NPIX;
        const bool vx1 = (unsigned)(ix + 1) < (unsigned)NPIX;
        const bool vy0 = (unsigned)iy       < (unsigned)NPIX;
        const bool vy1 = (unsigned)(iy + 1) < (unsigned)NPIX;
        float w00 = (vx0 && vy0) ? ax * ay : 0.0f;
        float w01 = (vx1 && vy0) ? wx * ay : 0.0f;
        float w10 = (vx0 && vy1) ? ax * wy : 0.0f;
        float w11 = (vx1 && vy1) ? wx * wy : 0.0f;
        // pair slot holds (v[xc0], v[xc0+1]); if ix<0 the valid x=0 value is
        // in slot 0 -> shift weights left (R4 trick)
        const bool xneg = (ix < 0);
        const v2f wv0 = { xneg ? w01 : w00, xneg ? 0.0f : w01 };
        const v2f wv1 = { xneg ? w11 : w10, xneg ? 0.0f : w11 };
        const int xc0 = min(max(ix,     0), NPIX - 1);
        const int yc0 = min(max(iy,     0), NPIX - 1);
        const int yc1 = min(max(iy + 1, 0), NPIX - 1);
        acc_row(pk[(yc0 << 9) + xc0], wv0, accp);
        acc_row(pk[(yc1 << 9) + xc0], wv1, accp);
    }

    // ---------------- interior loop: s < ie (no clamps/selects) ------------
    for (; s < ie; s += 4) {
        const float sf = (float)s;
        const float fx = fmaf(fxs, sf, fx0);
        const float fy = fmaf(fys, sf, fy0);
        const float x0f = floorf(fx), y0f = floorf(fy);
        const float wx = fx - x0f, wy = fy - y0f;
        const int ix = (int)x0f, iy = (int)y0f;
        const float ax = 1.0f - wx, ay = 1.0f - wy;
        const v2f axwx = { ax, wx };
        const v2f wv0 = axwx * ay;       // (w00, w01)
        const v2f wv1 = axwx * wy;       // (w10, w11)
        const int p0 = (iy << 9) + ix;
        acc_row(pk[p0],        wv0, accp);
        acc_row(pk[p0 + NPIX], wv1, accp);
    }

    // ---------------- border loop 2: s < s_end -----------------------------
    for (; s < s_end; s += 4) {
        const float sf = (float)s;
        const float fx = fmaf(fxs, sf, fx0);
        const float fy = fmaf(fys, sf, fy0);
        const float x0f = floorf(fx), y0f = floorf(fy);
        const float wx = fx - x0f, wy = fy - y0f;
        const int ix = (int)x0f, iy = (int)y0f;
        const float ax = 1.0f - wx, ay = 1.0f - wy;
        const bool vx0 = (unsigned)ix       < (unsigned)NPIX;
        const bool vx1 = (unsigned)(ix + 1) < (unsigned)NPIX;
        const bool vy0 = (unsigned)iy       < (unsigned)NPIX;
        const bool vy1 = (unsigned)(iy + 1) < (unsigned)NPIX;
        float w00 = (vx0 && vy0) ? ax * ay : 0.0f;
        float w01 = (vx1 && vy0) ? wx * ay : 0.0f;
        float w10 = (vx0 && vy1) ? ax * wy : 0.0f;
        float w11 = (vx1 && vy1) ? wx * wy : 0.0f;
        const bool xneg = (ix < 0);
        const v2f wv0 = { xneg ? w01 : w00, xneg ? 0.0f : w01 };
        const v2f wv1 = { xneg ? w11 : w10, xneg ? 0.0f : w11 };
        const int xc0 = min(max(ix,     0), NPIX - 1);
        const int yc0 = min(max(iy,     0), NPIX - 1);
        const int yc1 = min(max(iy + 1, 0), NPIX - 1);
        acc_row(pk[(yc0 << 9) + xc0], wv0, accp);
        acc_row(pk[(yc1 << 9) + xc0], wv1, accp);
    }

    // ---- fold x0/x1 halves, reduce the 4 soff partials, store -------------
    float acc[NBATCH];
#pragma unroll
    for (int b = 0; b < NBATCH; ++b) {
        acc[b] = accp[b].x + accp[b].y;
        acc[b] += __shfl_xor(acc[b], 16, 64);
        acc[b] += __shfl_xor(acc[b], 32, 64);
    }

    if (soff == 0) {
#pragma unroll
        for (int b = 0; b < NBATCH; ++b)
            out[((size_t)b * NVIEW + v) * NDET + d] = acc[b] * DT;
    }
}

// ---------------------------------------------------------------------------
// Fallback (original layout, fp32 scalar loads) — only if ws too small.
// ---------------------------------------------------------------------------
__global__ __launch_bounds__(256) void projector_kernel_fallback(
    const float* __restrict__ image, const float* __restrict__ views,
    float* __restrict__ out)
{
    const int d = blockIdx.x * blockDim.x + threadIdx.x;
    const int v = blockIdx.y;
    if (d >= NDET) return;

    const float PIX = 0.7433f, ISO = 595.0f;
    const float SDD_ = 595.0f + 490.6f;
    const float DGAM = 1.2858f / SDD_;
    const float FOV  = 512.0f * 0.7433f * 0.70710678f;
    const float T0   = ISO - FOV;
    const float DT   = 2.0f * FOV / (float)NSAMP;

    const float beta  = views[v];
    const float gamma = ((float)d - 0.5f * (float)(NDET - 1)) * DGAM;
    const float sx = ISO * cosf(beta), sy = ISO * sinf(beta);
    const float ang = beta + 3.14159265358979f + gamma;
    const float gx = cosf(ang) / PIX, gy = sinf(ang) / PIX;
    const float cx = sx / PIX + 0.5f * (float)(NPIX - 1);
    const float cy = sy / PIX + 0.5f * (float)(NPIX - 1);

    float acc[NBATCH];
#pragma unroll
    for (int b = 0; b < NBATCH; ++b) acc[b] = 0.0f;

    for (int s = 0; s < NSAMP; ++s) {
        const float t  = fmaf((float)s + 0.5f, DT, T0);
        const float fx = fmaf(gx, t, cx);
        const float fy = fmaf(gy, t, cy);
        const float x0f = floorf(fx), y0f = floorf(fy);
        const float wx = fx - x0f, wy = fy - y0f;
        const int ix = (int)x0f, iy = (int)y0f;
        const float ax = 1.0f - wx, ay = 1.0f - wy;
        const bool vx0 = (unsigned)ix < (unsigned)NPIX;
        const bool vx1 = (unsigned)(ix + 1) < (unsigned)NPIX;
        const bool vy0 = (unsigned)iy < (unsigned)NPIX;
        const bool vy1 = (unsigned)(iy + 1) < (unsigned)NPIX;
        const float w00 = (vx0 && vy0) ? ax * ay : 0.0f;
        const float w01 = (vx1 && vy0) ? wx * ay : 0.0f;
        const float w10 = (vx0 && vy1) ? ax * wy : 0.0f;
        const float w11 = (vx1 && vy1) ? wx * wy : 0.0f;
        const int xc0 = min(max(ix, 0), NPIX - 1);
        const int xc1 = min(max(ix + 1, 0), NPIX - 1);
        const int yc0 = min(max(iy, 0), NPIX - 1);
        const int yc1 = min(max(iy + 1, 0), NPIX - 1);
        const int i00 = (yc0 << 9) + xc0, i01 = (yc0 << 9) + xc1;
        const int i10 = (yc1 << 9) + xc0, i11 = (yc1 << 9) + xc1;
#pragma unroll
        for (int b = 0; b < NBATCH; ++b) {
            const float* img = image + (size_t)b * (NPIX * NPIX);
            acc[b] = fmaf(w00, img[i00], fmaf(w01, img[i01],
                     fmaf(w10, img[i10], fmaf(w11, img[i11], acc[b]))));
        }
    }
#pragma unroll
    for (int b = 0; b < NBATCH; ++b)
        out[((size_t)b * NVIEW + v) * NDET + d] = acc[b] * DT;
}

extern "C" void kernel_launch(void* const* d_in, const int* in_sizes, int n_in,
                              void* d_out, int out_size, void* d_ws, size_t ws_size,
                              hipStream_t stream) {
    const float* image = (const float*)d_in[0];
    const float* views = (const float*)d_in[1];
    float* out = (float*)d_out;

    const size_t packed_bytes = (size_t)NPIX * NPIX * sizeof(int4);
    // Host decides on ws_size ONLY (R7 lesson: __has_builtin is false in the
    // host pass — never let it pick the kernel).
    if (ws_size >= packed_bytes && d_ws != nullptr) {
        int4* packed = (int4*)d_ws;
        repack_kernel<<<dim3((NPIX * NPIX) / 256), dim3(256), 0, stream>>>(image, packed);
        projector_kernel<<<dim3(NDET / 64, NVIEW), dim3(256), 0, stream>>>(
            packed, views, out);
    } else {
        projector_kernel_fallback<<<dim3(NDET / 256, NVIEW), dim3(256), 0, stream>>>(image, views, out);
    }
}

// Round 10
// 286.299 us; speedup vs baseline: 41.5943x; 1.1627x over previous
//
#include <hip/hip_runtime.h>

#define NPIX   512
#define NDET   768
#define NSAMP  768
#define NVIEW  360
#define NBATCH 8

// u4 dot8: acc += sum_k nib_k(a)*nib_k(b).  Builtin gated in DEVICE pass only
// (R7 lesson: host-pass __has_builtin is false for amdgcn builtins).
__device__ __forceinline__ int udot8(int a, int b, int acc) {
#if defined(__HIP_DEVICE_COMPILE__) && defined(__has_builtin)
#if __has_builtin(__builtin_amdgcn_udot8)
    return (int)__builtin_amdgcn_udot8((unsigned)a, (unsigned)b, (unsigned)acc, false);
#define UDOT8_DONE 1
#endif
#endif
#ifndef UDOT8_DONE
#pragma unroll
    for (int k = 0; k < 8; ++k)
        acc += ((a >> (4 * k)) & 15) * ((b >> (4 * k)) & 15);
    return acc;
#endif
}

// ---------------------------------------------------------------------------
// Repack image [8,512,512] fp32 -> u4 quad-pack, NIBBLE-INTERLEAVED batches:
//   pixel (y,x), dword d (d=0..3) = batches {2d (even nibbles), 2d+1 (odd)}:
//     nibble 2c   = round(15*v[2d  ]) at corner c
//     nibble 2c+1 = round(15*v[2d+1]) at corner c
//   corners c: 0=(x,y) 1=(x+1,y) 2=(x,y+1) 3=(x+1,y+1)   (clamped)
// ONE dwordx4 gather = all 4 bilinear corners x all 8 batches.
// Footprint 4 MB -> L2-resident (R4 lesson: 8 MB thrashes).
// R9 lesson: weights need 8-bit precision -> dual lo/hi nibble masks from the
// SAME byte-packed weight word; interleaving makes both masks 1-2 ops each.
// ---------------------------------------------------------------------------
__global__ __launch_bounds__(256) void repack_kernel(
    const float* __restrict__ image,    // [8, 512, 512]
    int4* __restrict__ packed)          // [512*512]
{
    const int idx = blockIdx.x * blockDim.x + threadIdx.x;  // (y<<9)|x
    if (idx >= NPIX * NPIX) return;
    const int x  = idx & (NPIX - 1);
    const int y  = idx >> 9;
    const int x1 = min(x + 1, NPIX - 1);
    const int y1 = min(y + 1, NPIX - 1);
    const int c0 = (y << 9) + x, c1 = (y << 9) + x1;
    const int c2 = (y1 << 9) + x, c3 = (y1 << 9) + x1;
    int w[4];
#pragma unroll
    for (int d = 0; d < 4; ++d) {
        const float* imgA = image + (size_t)(2 * d)     * (NPIX * NPIX);
        const float* imgB = image + (size_t)(2 * d + 1) * (NPIX * NPIX);
        const int a0 = (int)(imgA[c0] * 15.0f + 0.5f);
        const int a1 = (int)(imgA[c1] * 15.0f + 0.5f);
        const int a2 = (int)(imgA[c2] * 15.0f + 0.5f);
        const int a3 = (int)(imgA[c3] * 15.0f + 0.5f);
        const int b0 = (int)(imgB[c0] * 15.0f + 0.5f);
        const int b1 = (int)(imgB[c1] * 15.0f + 0.5f);
        const int b2 = (int)(imgB[c2] * 15.0f + 0.5f);
        const int b3 = (int)(imgB[c3] * 15.0f + 0.5f);
        w[d] = a0 | (b0 << 4) | (a1 << 8)  | (b1 << 12)
             | (a2 << 16) | (b2 << 20) | (a3 << 24) | (b3 << 28);
    }
    packed[idx] = make_int4(w[0], w[1], w[2], w[3]);
}

// Accumulate one sample. Q = 4 weights byte-packed (u8 = 16*wh + wl).
// Even-nibble masks hit even-batch values, odd-nibble masks hit odd-batch.
__device__ __forceinline__ void acc_quad(const int4 q, const int Q,
                                         int accL[NBATCH], int accH[NBATCH]) {
    const int mAlo = Q & 0x0F0F0F0F;
    const int mAhi = (int)(((unsigned)Q >> 4) & 0x0F0F0F0F);
    const int mBlo = mAlo << 4;
    const int mBhi = Q & (int)0xF0F0F0F0;
    accL[0] = udot8(q.x, mAlo, accL[0]);  accH[0] = udot8(q.x, mAhi, accH[0]);
    accL[1] = udot8(q.x, mBlo, accL[1]);  accH[1] = udot8(q.x, mBhi, accH[1]);
    accL[2] = udot8(q.y, mAlo, accL[2]);  accH[2] = udot8(q.y, mAhi, accH[2]);
    accL[3] = udot8(q.y, mBlo, accL[3]);  accH[3] = udot8(q.y, mBhi, accH[3]);
    accL[4] = udot8(q.z, mAlo, accL[4]);  accH[4] = udot8(q.z, mAhi, accH[4]);
    accL[5] = udot8(q.z, mBlo, accL[5]);  accH[5] = udot8(q.z, mBhi, accH[5]);
    accL[6] = udot8(q.w, mAlo, accL[6]);  accH[6] = udot8(q.w, mAhi, accH[6]);
    accL[7] = udot8(q.w, mBlo, accL[7]);  accH[7] = udot8(q.w, mBhi, accH[7]);
}

// byte-pack 4 weights quantized to u8 (255 scale)
__device__ __forceinline__ int pack_w8(float w00, float w01, float w10, float w11) {
    const int u0 = (int)(w00 * 255.0f + 0.5f);
    const int u1 = (int)(w01 * 255.0f + 0.5f);
    const int u2 = (int)(w10 * 255.0f + 0.5f);
    const int u3 = (int)(w11 * 255.0f + 0.5f);
    return u0 | (u1 << 8) | (u2 << 16) | (u3 << 24);
}

// ---------------------------------------------------------------------------
// Main projector. Wave = 16 detectors x 4 sample-offsets (R6 patch locality).
// Per sample: ONE dwordx4 gather + 16 v_dot8 (8-bit-exact weights).
// ---------------------------------------------------------------------------
__global__ __launch_bounds__(256) void projector_kernel(
    const int4* __restrict__ pk,        // [512*512] u4 quad-pack interleaved
    const float* __restrict__ views,    // [360]
    float* __restrict__ out)            // [8, 360, 768]
{
    const int lane    = threadIdx.x & 63;
    const int wave    = threadIdx.x >> 6;
    const int detlane = lane & 15;
    const int soff    = lane >> 4;
    const int d = blockIdx.x * 64 + wave * 16 + detlane;
    const int v = blockIdx.y;

    const float PIX   = 0.7433f;
    const float ISO   = 595.0f;
    const float SDD_  = 595.0f + 490.6f;
    const float DGAM  = 1.2858f / SDD_;
    const float FOV   = 512.0f * 0.7433f * 0.70710678f;
    const float T0    = ISO - FOV;
    const float DT    = 2.0f * FOV / (float)NSAMP;

    const float beta  = views[v];
    const float gamma = ((float)d - 0.5f * (float)(NDET - 1)) * DGAM;
    const float sx = ISO * cosf(beta);
    const float sy = ISO * sinf(beta);
    const float ang = beta + 3.14159265358979f + gamma;
    const float gx = cosf(ang) / PIX;
    const float gy = sinf(ang) / PIX;
    const float cx = sx / PIX + 0.5f * (float)(NPIX - 1);
    const float cy = sy / PIX + 0.5f * (float)(NPIX - 1);

    // ---- clip sample range to padded image box (pad 3 px; outside = 0) ----
    const float PLO = -3.0f, PHI = (float)NPIX + 2.0f;
    float lo = T0 + 0.5f * DT;
    float hi = T0 + ((float)NSAMP - 0.5f) * DT;
    if (fabsf(gx) > 1e-8f) {
        float ta = (PLO - cx) / gx, tb = (PHI - cx) / gx;
        lo = fmaxf(lo, fminf(ta, tb));
        hi = fminf(hi, fmaxf(ta, tb));
    } else if (cx < PLO || cx > PHI) {
        hi = lo - 1.0f;
    }
    if (fabsf(gy) > 1e-8f) {
        float ta = (PLO - cy) / gy, tb = (PHI - cy) / gy;
        lo = fmaxf(lo, fminf(ta, tb));
        hi = fminf(hi, fmaxf(ta, tb));
    } else if (cy < PLO || cy > PHI) {
        hi = lo - 1.0f;
    }

    int s_begin = 0, s_end = 0;
    if (hi >= lo) {
        s_begin = max(0, (int)floorf((lo - T0) / DT - 0.5f));
        s_end   = min(NSAMP, (int)ceilf((hi - T0) / DT - 0.5f) + 1);
    }

    // ---- interior range: strictly inside [0.01, 510.99]^2 (no clamping) ---
    const float XLO = 0.01f, XHI = 510.99f;
    float ilo = lo, ihi = hi;
    if (fabsf(gx) > 1e-8f) {
        float ta = (XLO - cx) / gx, tb = (XHI - cx) / gx;
        ilo = fmaxf(ilo, fminf(ta, tb));
        ihi = fminf(ihi, fmaxf(ta, tb));
    } else if (cx < XLO || cx > XHI) {
        ihi = ilo - 1.0f;
    }
    if (fabsf(gy) > 1e-8f) {
        float ta = (XLO - cy) / gy, tb = (XHI - cy) / gy;
        ilo = fmaxf(ilo, fminf(ta, tb));
        ihi = fminf(ihi, fmaxf(ta, tb));
    } else if (cy < XLO || cy > XHI) {
        ihi = ilo - 1.0f;
    }

    int ib = s_begin, ie = s_begin;
    if (ihi >= ilo) {
        ib = max(s_begin, (int)ceilf ((ilo - T0) / DT - 0.5f));
        ie = min(s_end,   (int)floorf((ihi - T0) / DT - 0.5f) + 1);
        if (ie < ib) { ib = s_begin; ie = s_begin; }
    }

    const float fxs = gx * DT;
    const float fys = gy * DT;
    const float fx0 = fmaf(gx, T0 + 0.5f * DT, cx);
    const float fy0 = fmaf(gy, T0 + 0.5f * DT, cy);

    int accL[NBATCH], accH[NBATCH];
#pragma unroll
    for (int b = 0; b < NBATCH; ++b) { accL[b] = 0; accH[b] = 0; }

    int s = s_begin + soff;          // this thread's samples: step 4

    // ---------------- border loop 1: s < ib --------------------------------
    for (; s < ib; s += 4) {
        const float sf = (float)s;
        const float fx = fmaf(fxs, sf, fx0);
        const float fy = fmaf(fys, sf, fy0);
        const float x0f = floorf(fx), y0f = floorf(fy);
        const float wx = fx - x0f, wy = fy - y0f;
        const int ix = (int)x0f, iy = (int)y0f;
        const float ax = 1.0f - wx, ay = 1.0f - wy;
        const bool vx0 = (unsigned)ix       < (unsigned)NPIX;
        const bool vx1 = (unsigned)(ix + 1) < (unsigned)NPIX;
        const bool vy0 = (unsigned)iy       < (unsigned)NPIX;
        const bool vy1 = (unsigned)(iy + 1) < (unsigned)NPIX;
        float w00 = (vx0 && vy0) ? ax * ay : 0.0f;
        float w01 = (vx1 && vy0) ? wx * ay : 0.0f;
        float w10 = (vx0 && vy1) ? ax * wy : 0.0f;
        float w11 = (vx1 && vy1) ? wx * wy : 0.0f;
        // clamped pixel holds corners (x..x+1, y..y+1); when ix<0 / iy<0 the
        // valid corner sits in the +1 slot -> shift weights toward slot 0.
        const bool xneg = (ix < 0);
        float s00 = xneg ? w01 : w00, s01 = xneg ? 0.0f : w01;
        float s10 = xneg ? w11 : w10, s11 = xneg ? 0.0f : w11;
        const bool yneg = (iy < 0);
        const float t00 = yneg ? s10 : s00, t10 = yneg ? 0.0f : s10;
        const float t01 = yneg ? s11 : s01, t11 = yneg ? 0.0f : s11;
        const int px = min(max(ix, 0), NPIX - 1);
        const int py = min(max(iy, 0), NPIX - 1);
        acc_quad(pk[(py << 9) + px], pack_w8(t00, t01, t10, t11), accL, accH);
    }

    // ---------------- interior loop: s < ie (no clamps/selects) ------------
    for (; s < ie; s += 4) {
        const float sf = (float)s;
        const float fx = fmaf(fxs, sf, fx0);
        const float fy = fmaf(fys, sf, fy0);
        const float x0f = floorf(fx), y0f = floorf(fy);
        const float wx = fx - x0f, wy = fy - y0f;
        const int ix = (int)x0f, iy = (int)y0f;
        const float ax = 1.0f - wx, ay = 1.0f - wy;
        acc_quad(pk[(iy << 9) + ix],
                 pack_w8(ax * ay, wx * ay, ax * wy, wx * wy), accL, accH);
    }

    // ---------------- border loop 2: s < s_end -----------------------------
    for (; s < s_end; s += 4) {
        const float sf = (float)s;
        const float fx = fmaf(fxs, sf, fx0);
        const float fy = fmaf(fys, sf, fy0);
        const float x0f = floorf(fx), y0f = floorf(fy);
        const float wx = fx - x0f, wy = fy - y0f;
        const int ix = (int)x0f, iy = (int)y0f;
        const float ax = 1.0f - wx, ay = 1.0f - wy;
        const bool vx0 = (unsigned)ix       < (unsigned)NPIX;
        const bool vx1 = (unsigned)(ix + 1) < (unsigned)NPIX;
        const bool vy0 = (unsigned)iy       < (unsigned)NPIX;
        const bool vy1 = (unsigned)(iy + 1) < (unsigned)NPIX;
        float w00 = (vx0 && vy0) ? ax * ay : 0.0f;
        float w01 = (vx1 && vy0) ? wx * ay : 0.0f;
        float w10 = (vx0 && vy1) ? ax * wy : 0.0f;
        float w11 = (vx1 && vy1) ? wx * wy : 0.0f;
        const bool xneg = (ix < 0);
        float s00 = xneg ? w01 : w00, s01 = xneg ? 0.0f : w01;
        float s10 = xneg ? w11 : w10, s11 = xneg ? 0.0f : w11;
        const bool yneg = (iy < 0);
        const float t00 = yneg ? s10 : s00, t10 = yneg ? 0.0f : s10;
        const float t01 = yneg ? s11 : s01, t11 = yneg ? 0.0f : s11;
        const int px = min(max(ix, 0), NPIX - 1);
        const int py = min(max(iy, 0), NPIX - 1);
        acc_quad(pk[(py << 9) + px], pack_w8(t00, t01, t10, t11), accL, accH);
    }

    // ---- combine hi/lo, reduce the 4 soff partials, scale, store ----------
#pragma unroll
    for (int b = 0; b < NBATCH; ++b) {
        int a = accH[b] * 16 + accL[b];
        a += __shfl_xor(a, 16, 64);
        a += __shfl_xor(a, 32, 64);
        accL[b] = a;
    }

    if (soff == 0) {
        const float SCALE = DT * (1.0f / (15.0f * 255.0f));
#pragma unroll
        for (int b = 0; b < NBATCH; ++b)
            out[((size_t)b * NVIEW + v) * NDET + d] = (float)accL[b] * SCALE;
    }
}

// ---------------------------------------------------------------------------
// Fallback (original layout, fp32 scalar loads) — only if ws too small.
// ---------------------------------------------------------------------------
__global__ __launch_bounds__(256) void projector_kernel_fallback(
    const float* __restrict__ image, const float* __restrict__ views,
    float* __restrict__ out)
{
    const int d = blockIdx.x * blockDim.x + threadIdx.x;
    const int v = blockIdx.y;
    if (d >= NDET) return;

    const float PIX = 0.7433f, ISO = 595.0f;
    const float SDD_ = 595.0f + 490.6f;
    const float DGAM = 1.2858f / SDD_;
    const float FOV  = 512.0f * 0.7433f * 0.70710678f;
    const float T0   = ISO - FOV;
    const float DT   = 2.0f * FOV / (float)NSAMP;

    const float beta  = views[v];
    const float gamma = ((float)d - 0.5f * (float)(NDET - 1)) * DGAM;
    const float sx = ISO * cosf(beta), sy = ISO * sinf(beta);
    const float ang = beta + 3.14159265358979f + gamma;
    const float gx = cosf(ang) / PIX, gy = sinf(ang) / PIX;
    const float cx = sx / PIX + 0.5f * (float)(NPIX - 1);
    const float cy = sy / PIX + 0.5f * (float)(NPIX - 1);

    float acc[NBATCH];
#pragma unroll
    for (int b = 0; b < NBATCH; ++b) acc[b] = 0.0f;

    for (int s = 0; s < NSAMP; ++s) {
        const float t  = fmaf((float)s + 0.5f, DT, T0);
        const float fx = fmaf(gx, t, cx);
        const float fy = fmaf(gy, t, cy);
        const float x0f = floorf(fx), y0f = floorf(fy);
        const float wx = fx - x0f, wy = fy - y0f;
        const int ix = (int)x0f, iy = (int)y0f;
        const float ax = 1.0f - wx, ay = 1.0f - wy;
        const bool vx0 = (unsigned)ix < (unsigned)NPIX;
        const bool vx1 = (unsigned)(ix + 1) < (unsigned)NPIX;
        const bool vy0 = (unsigned)iy < (unsigned)NPIX;
        const bool vy1 = (unsigned)(iy + 1) < (unsigned)NPIX;
        const float w00 = (vx0 && vy0) ? ax * ay : 0.0f;
        const float w01 = (vx1 && vy0) ? wx * ay : 0.0f;
        const float w10 = (vx0 && vy1) ? ax * wy : 0.0f;
        const float w11 = (vx1 && vy1) ? wx * wy : 0.0f;
        const int xc0 = min(max(ix, 0), NPIX - 1);
        const int xc1 = min(max(ix + 1, 0), NPIX - 1);
        const int yc0 = min(max(iy, 0), NPIX - 1);
        const int yc1 = min(max(iy + 1, 0), NPIX - 1);
        const int i00 = (yc0 << 9) + xc0, i01 = (yc0 << 9) + xc1;
        const int i10 = (yc1 << 9) + xc0, i11 = (yc1 << 9) + xc1;
#pragma unroll
        for (int b = 0; b < NBATCH; ++b) {
            const float* img = image + (size_t)b * (NPIX * NPIX);
            acc[b] = fmaf(w00, img[i00], fmaf(w01, img[i01],
                     fmaf(w10, img[i10], fmaf(w11, img[i11], acc[b]))));
        }
    }
#pragma unroll
    for (int b = 0; b < NBATCH; ++b)
        out[((size_t)b * NVIEW + v) * NDET + d] = acc[b] * DT;
}

extern "C" void kernel_launch(void* const* d_in, const int* in_sizes, int n_in,
                              void* d_out, int out_size, void* d_ws, size_t ws_size,
                              hipStream_t stream) {
    const float* image = (const float*)d_in[0];
    const float* views = (const float*)d_in[1];
    float* out = (float*)d_out;

    const size_t packed_bytes = (size_t)NPIX * NPIX * sizeof(int4);
    if (ws_size >= packed_bytes && d_ws != nullptr) {
        int4* packed = (int4*)d_ws;
        repack_kernel<<<dim3((NPIX * NPIX) / 256), dim3(256), 0, stream>>>(image, packed);
        projector_kernel<<<dim3(NDET / 64, NVIEW), dim3(256), 0, stream>>>(
            packed, views, out);
    } else {
        projector_kernel_fallback<<<dim3(NDET / 256, NVIEW), dim3(256), 0, stream>>>(image, views, out);
    }
}

// Round 11
// 282.691 us; speedup vs baseline: 42.1252x; 1.0128x over previous
//
#include <hip/hip_runtime.h>

#define NPIX   512
#define NDET   768
#define NSAMP  768
#define NVIEW  360
#define NBATCH 8

// u4 dot8: acc += sum_k nib_k(a)*nib_k(b).  Builtin gated in DEVICE pass only
// (R7 lesson: host-pass __has_builtin is false for amdgcn builtins).
__device__ __forceinline__ int udot8(int a, int b, int acc) {
#if defined(__HIP_DEVICE_COMPILE__) && defined(__has_builtin)
#if __has_builtin(__builtin_amdgcn_udot8)
    return (int)__builtin_amdgcn_udot8((unsigned)a, (unsigned)b, (unsigned)acc, false);
#define UDOT8_DONE 1
#endif
#endif
#ifndef UDOT8_DONE
#pragma unroll
    for (int k = 0; k < 8; ++k)
        acc += ((a >> (4 * k)) & 15) * ((b >> (4 * k)) & 15);
    return acc;
#endif
}

// ---------------------------------------------------------------------------
// Repack image [8,512,512] fp32 -> u4 quad-pack, NIBBLE-INTERLEAVED batches:
//   pixel (y,x), dword d (d=0..3) = batches {2d (even nibbles), 2d+1 (odd)}:
//     nibble 2c   = round(15*v[2d  ]) at corner c
//     nibble 2c+1 = round(15*v[2d+1]) at corner c
//   corners c: 0=(x,y) 1=(x+1,y) 2=(x,y+1) 3=(x+1,y+1)   (clamped)
// ONE dwordx4 gather = all 4 bilinear corners x all 8 batches.
// Footprint 4 MB -> L2-resident (R4 lesson: 8 MB thrashes).
// R9 lesson: weights need 8-bit precision -> dual lo/hi nibble masks.
// ---------------------------------------------------------------------------
__global__ __launch_bounds__(256) void repack_kernel(
    const float* __restrict__ image,    // [8, 512, 512]
    int4* __restrict__ packed)          // [512*512]
{
    const int idx = blockIdx.x * blockDim.x + threadIdx.x;  // (y<<9)|x
    if (idx >= NPIX * NPIX) return;
    const int x  = idx & (NPIX - 1);
    const int y  = idx >> 9;
    const int x1 = min(x + 1, NPIX - 1);
    const int y1 = min(y + 1, NPIX - 1);
    const int c0 = (y << 9) + x, c1 = (y << 9) + x1;
    const int c2 = (y1 << 9) + x, c3 = (y1 << 9) + x1;
    int w[4];
#pragma unroll
    for (int d = 0; d < 4; ++d) {
        const float* imgA = image + (size_t)(2 * d)     * (NPIX * NPIX);
        const float* imgB = image + (size_t)(2 * d + 1) * (NPIX * NPIX);
        const int a0 = (int)(imgA[c0] * 15.0f + 0.5f);
        const int a1 = (int)(imgA[c1] * 15.0f + 0.5f);
        const int a2 = (int)(imgA[c2] * 15.0f + 0.5f);
        const int a3 = (int)(imgA[c3] * 15.0f + 0.5f);
        const int b0 = (int)(imgB[c0] * 15.0f + 0.5f);
        const int b1 = (int)(imgB[c1] * 15.0f + 0.5f);
        const int b2 = (int)(imgB[c2] * 15.0f + 0.5f);
        const int b3 = (int)(imgB[c3] * 15.0f + 0.5f);
        w[d] = a0 | (b0 << 4) | (a1 << 8)  | (b1 << 12)
             | (a2 << 16) | (b2 << 20) | (a3 << 24) | (b3 << 28);
    }
    packed[idx] = make_int4(w[0], w[1], w[2], w[3]);
}

// Accumulate one sample. Q = 4 weights byte-packed (u8 = 16*wh + wl).
// Even-nibble masks hit even-batch values, odd-nibble masks hit odd-batch.
__device__ __forceinline__ void acc_quad(const int4 q, const int Q,
                                         int accL[NBATCH], int accH[NBATCH]) {
    const int mAlo = Q & 0x0F0F0F0F;
    const int mAhi = (int)(((unsigned)Q >> 4) & 0x0F0F0F0F);
    const int mBlo = mAlo << 4;
    const int mBhi = Q & (int)0xF0F0F0F0;
    accL[0] = udot8(q.x, mAlo, accL[0]);  accH[0] = udot8(q.x, mAhi, accH[0]);
    accL[1] = udot8(q.x, mBlo, accL[1]);  accH[1] = udot8(q.x, mBhi, accH[1]);
    accL[2] = udot8(q.y, mAlo, accL[2]);  accH[2] = udot8(q.y, mAhi, accH[2]);
    accL[3] = udot8(q.y, mBlo, accL[3]);  accH[3] = udot8(q.y, mBhi, accH[3]);
    accL[4] = udot8(q.z, mAlo, accL[4]);  accH[4] = udot8(q.z, mAhi, accH[4]);
    accL[5] = udot8(q.z, mBlo, accL[5]);  accH[5] = udot8(q.z, mBhi, accH[5]);
    accL[6] = udot8(q.w, mAlo, accL[6]);  accH[6] = udot8(q.w, mAhi, accH[6]);
    accL[7] = udot8(q.w, mBlo, accL[7]);  accH[7] = udot8(q.w, mBhi, accH[7]);
}

// byte-pack 4 weights quantized to u8 (255 scale)
__device__ __forceinline__ int pack_w8(float w00, float w01, float w10, float w11) {
    const int u0 = (int)(w00 * 255.0f + 0.5f);
    const int u1 = (int)(w01 * 255.0f + 0.5f);
    const int u2 = (int)(w10 * 255.0f + 0.5f);
    const int u3 = (int)(w11 * 255.0f + 0.5f);
    return u0 | (u1 << 8) | (u2 << 16) | (u3 << 24);
}

// ---------------------------------------------------------------------------
// Main projector. Wave = 16 detectors x 4 sample-offsets (R6 patch locality).
// Per sample: ONE dwordx4 gather + 16 v_dot8 (8-bit-exact weights).
// R11: interior loop software-pipelined — the gather for sample s+4 is issued
// before the udot8 bundle consuming sample s (load->use distance = 1 full
// iteration; R10's ~15-instr distance left ~95 µs of vmcnt stall).
// ---------------------------------------------------------------------------
__global__ __launch_bounds__(256) void projector_kernel(
    const int4* __restrict__ pk,        // [512*512] u4 quad-pack interleaved
    const float* __restrict__ views,    // [360]
    float* __restrict__ out)            // [8, 360, 768]
{
    const int lane    = threadIdx.x & 63;
    const int wave    = threadIdx.x >> 6;
    const int detlane = lane & 15;
    const int soff    = lane >> 4;
    const int d = blockIdx.x * 64 + wave * 16 + detlane;
    const int v = blockIdx.y;

    const float PIX   = 0.7433f;
    const float ISO   = 595.0f;
    const float SDD_  = 595.0f + 490.6f;
    const float DGAM  = 1.2858f / SDD_;
    const float FOV   = 512.0f * 0.7433f * 0.70710678f;
    const float T0    = ISO - FOV;
    const float DT    = 2.0f * FOV / (float)NSAMP;

    const float beta  = views[v];
    const float gamma = ((float)d - 0.5f * (float)(NDET - 1)) * DGAM;
    const float sx = ISO * cosf(beta);
    const float sy = ISO * sinf(beta);
    const float ang = beta + 3.14159265358979f + gamma;
    const float gx = cosf(ang) / PIX;
    const float gy = sinf(ang) / PIX;
    const float cx = sx / PIX + 0.5f * (float)(NPIX - 1);
    const float cy = sy / PIX + 0.5f * (float)(NPIX - 1);

    // ---- clip sample range to padded image box (pad 3 px; outside = 0) ----
    const float PLO = -3.0f, PHI = (float)NPIX + 2.0f;
    float lo = T0 + 0.5f * DT;
    float hi = T0 + ((float)NSAMP - 0.5f) * DT;
    if (fabsf(gx) > 1e-8f) {
        float ta = (PLO - cx) / gx, tb = (PHI - cx) / gx;
        lo = fmaxf(lo, fminf(ta, tb));
        hi = fminf(hi, fmaxf(ta, tb));
    } else if (cx < PLO || cx > PHI) {
        hi = lo - 1.0f;
    }
    if (fabsf(gy) > 1e-8f) {
        float ta = (PLO - cy) / gy, tb = (PHI - cy) / gy;
        lo = fmaxf(lo, fminf(ta, tb));
        hi = fminf(hi, fmaxf(ta, tb));
    } else if (cy < PLO || cy > PHI) {
        hi = lo - 1.0f;
    }

    int s_begin = 0, s_end = 0;
    if (hi >= lo) {
        s_begin = max(0, (int)floorf((lo - T0) / DT - 0.5f));
        s_end   = min(NSAMP, (int)ceilf((hi - T0) / DT - 0.5f) + 1);
    }

    // ---- interior range: strictly inside [0.01, 510.99]^2 (no clamping) ---
    const float XLO = 0.01f, XHI = 510.99f;
    float ilo = lo, ihi = hi;
    if (fabsf(gx) > 1e-8f) {
        float ta = (XLO - cx) / gx, tb = (XHI - cx) / gx;
        ilo = fmaxf(ilo, fminf(ta, tb));
        ihi = fminf(ihi, fmaxf(ta, tb));
    } else if (cx < XLO || cx > XHI) {
        ihi = ilo - 1.0f;
    }
    if (fabsf(gy) > 1e-8f) {
        float ta = (XLO - cy) / gy, tb = (XHI - cy) / gy;
        ilo = fmaxf(ilo, fminf(ta, tb));
        ihi = fminf(ihi, fmaxf(ta, tb));
    } else if (cy < XLO || cy > XHI) {
        ihi = ilo - 1.0f;
    }

    int ib = s_begin, ie = s_begin;
    if (ihi >= ilo) {
        ib = max(s_begin, (int)ceilf ((ilo - T0) / DT - 0.5f));
        ie = min(s_end,   (int)floorf((ihi - T0) / DT - 0.5f) + 1);
        if (ie < ib) { ib = s_begin; ie = s_begin; }
    }

    const float fxs = gx * DT;
    const float fys = gy * DT;
    const float fx0 = fmaf(gx, T0 + 0.5f * DT, cx);
    const float fy0 = fmaf(gy, T0 + 0.5f * DT, cy);

    int accL[NBATCH], accH[NBATCH];
#pragma unroll
    for (int b = 0; b < NBATCH; ++b) { accL[b] = 0; accH[b] = 0; }

    int s = s_begin + soff;          // this thread's samples: step 4

    // ---------------- border loop 1: s < ib --------------------------------
    for (; s < ib; s += 4) {
        const float sf = (float)s;
        const float fx = fmaf(fxs, sf, fx0);
        const float fy = fmaf(fys, sf, fy0);
        const float x0f = floorf(fx), y0f = floorf(fy);
        const float wx = fx - x0f, wy = fy - y0f;
        const int ix = (int)x0f, iy = (int)y0f;
        const float ax = 1.0f - wx, ay = 1.0f - wy;
        const bool vx0 = (unsigned)ix       < (unsigned)NPIX;
        const bool vx1 = (unsigned)(ix + 1) < (unsigned)NPIX;
        const bool vy0 = (unsigned)iy       < (unsigned)NPIX;
        const bool vy1 = (unsigned)(iy + 1) < (unsigned)NPIX;
        float w00 = (vx0 && vy0) ? ax * ay : 0.0f;
        float w01 = (vx1 && vy0) ? wx * ay : 0.0f;
        float w10 = (vx0 && vy1) ? ax * wy : 0.0f;
        float w11 = (vx1 && vy1) ? wx * wy : 0.0f;
        const bool xneg = (ix < 0);
        float s00 = xneg ? w01 : w00, s01 = xneg ? 0.0f : w01;
        float s10 = xneg ? w11 : w10, s11 = xneg ? 0.0f : w11;
        const bool yneg = (iy < 0);
        const float t00 = yneg ? s10 : s00, t10 = yneg ? 0.0f : s10;
        const float t01 = yneg ? s11 : s01, t11 = yneg ? 0.0f : s11;
        const int px = min(max(ix, 0), NPIX - 1);
        const int py = min(max(iy, 0), NPIX - 1);
        acc_quad(pk[(py << 9) + px], pack_w8(t00, t01, t10, t11), accL, accH);
    }

    // ------- interior loop: s < ie, software-pipelined (prefetch q) --------
    if (s < ie) {
        float fx = fmaf(fxs, (float)s, fx0);
        float fy = fmaf(fys, (float)s, fy0);
        float x0f = floorf(fx), y0f = floorf(fy);
        float wxc = fx - x0f, wyc = fy - y0f;
        int4 q = pk[((int)y0f << 9) + (int)x0f];
        int sn = s + 4;
        for (; sn < ie; sn += 4) {
            // issue NEXT gather first (no dependency on current consume)
            const float fx2 = fmaf(fxs, (float)sn, fx0);
            const float fy2 = fmaf(fys, (float)sn, fy0);
            const float x2f = floorf(fx2), y2f = floorf(fy2);
            const int4 q2 = pk[((int)y2f << 9) + (int)x2f];
            // consume CURRENT sample
            const float ax = 1.0f - wxc, ay = 1.0f - wyc;
            acc_quad(q, pack_w8(ax * ay, wxc * ay, ax * wyc, wxc * wyc),
                     accL, accH);
            // rotate
            q = q2; wxc = fx2 - x2f; wyc = fy2 - y2f;
        }
        // epilogue: consume last pending sample
        const float ax = 1.0f - wxc, ay = 1.0f - wyc;
        acc_quad(q, pack_w8(ax * ay, wxc * ay, ax * wyc, wxc * wyc),
                 accL, accH);
        s = sn;
    }

    // ---------------- border loop 2: s < s_end -----------------------------
    for (; s < s_end; s += 4) {
        const float sf = (float)s;
        const float fx = fmaf(fxs, sf, fx0);
        const float fy = fmaf(fys, sf, fy0);
        const float x0f = floorf(fx), y0f = floorf(fy);
        const float wx = fx - x0f, wy = fy - y0f;
        const int ix = (int)x0f, iy = (int)y0f;
        const float ax = 1.0f - wx, ay = 1.0f - wy;
        const bool vx0 = (unsigned)ix       < (unsigned)NPIX;
        const bool vx1 = (unsigned)(ix + 1) < (unsigned)NPIX;
        const bool vy0 = (unsigned)iy       < (unsigned)NPIX;
        const bool vy1 = (unsigned)(iy + 1) < (unsigned)NPIX;
        float w00 = (vx0 && vy0) ? ax * ay : 0.0f;
        float w01 = (vx1 && vy0) ? wx * ay : 0.0f;
        float w10 = (vx0 && vy1) ? ax * wy : 0.0f;
        float w11 = (vx1 && vy1) ? wx * wy : 0.0f;
        const bool xneg = (ix < 0);
        float s00 = xneg ? w01 : w00, s01 = xneg ? 0.0f : w01;
        float s10 = xneg ? w11 : w10, s11 = xneg ? 0.0f : w11;
        const bool yneg = (iy < 0);
        const float t00 = yneg ? s10 : s00, t10 = yneg ? 0.0f : s10;
        const float t01 = yneg ? s11 : s01, t11 = yneg ? 0.0f : s11;
        const int px = min(max(ix, 0), NPIX - 1);
        const int py = min(max(iy, 0), NPIX - 1);
        acc_quad(pk[(py << 9) + px], pack_w8(t00, t01, t10, t11), accL, accH);
    }

    // ---- combine hi/lo, reduce the 4 soff partials, scale, store ----------
#pragma unroll
    for (int b = 0; b < NBATCH; ++b) {
        int a = accH[b] * 16 + accL[b];
        a += __shfl_xor(a, 16, 64);
        a += __shfl_xor(a, 32, 64);
        accL[b] = a;
    }

    if (soff == 0) {
        const float SCALE = DT * (1.0f / (15.0f * 255.0f));
#pragma unroll
        for (int b = 0; b < NBATCH; ++b)
            out[((size_t)b * NVIEW + v) * NDET + d] = (float)accL[b] * SCALE;
    }
}

// ---------------------------------------------------------------------------
// Fallback (original layout, fp32 scalar loads) — only if ws too small.
// ---------------------------------------------------------------------------
__global__ __launch_bounds__(256) void projector_kernel_fallback(
    const float* __restrict__ image, const float* __restrict__ views,
    float* __restrict__ out)
{
    const int d = blockIdx.x * blockDim.x + threadIdx.x;
    const int v = blockIdx.y;
    if (d >= NDET) return;

    const float PIX = 0.7433f, ISO = 595.0f;
    const float SDD_ = 595.0f + 490.6f;
    const float DGAM = 1.2858f / SDD_;
    const float FOV  = 512.0f * 0.7433f * 0.70710678f;
    const float T0   = ISO - FOV;
    const float DT   = 2.0f * FOV / (float)NSAMP;

    const float beta  = views[v];
    const float gamma = ((float)d - 0.5f * (float)(NDET - 1)) * DGAM;
    const float sx = ISO * cosf(beta), sy = ISO * sinf(beta);
    const float ang = beta + 3.14159265358979f + gamma;
    const float gx = cosf(ang) / PIX, gy = sinf(ang) / PIX;
    const float cx = sx / PIX + 0.5f * (float)(NPIX - 1);
    const float cy = sy / PIX + 0.5f * (float)(NPIX - 1);

    float acc[NBATCH];
#pragma unroll
    for (int b = 0; b < NBATCH; ++b) acc[b] = 0.0f;

    for (int s = 0; s < NSAMP; ++s) {
        const float t  = fmaf((float)s + 0.5f, DT, T0);
        const float fx = fmaf(gx, t, cx);
        const float fy = fmaf(gy, t, cy);
        const float x0f = floorf(fx), y0f = floorf(fy);
        const float wx = fx - x0f, wy = fy - y0f;
        const int ix = (int)x0f, iy = (int)y0f;
        const float ax = 1.0f - wx, ay = 1.0f - wy;
        const bool vx0 = (unsigned)ix < (unsigned)NPIX;
        const bool vx1 = (unsigned)(ix + 1) < (unsigned)NPIX;
        const bool vy0 = (unsigned)iy < (unsigned)NPIX;
        const bool vy1 = (unsigned)(iy + 1) < (unsigned)NPIX;
        const float w00 = (vx0 && vy0) ? ax * ay : 0.0f;
        const float w01 = (vx1 && vy0) ? wx * ay : 0.0f;
        const float w10 = (vx0 && vy1) ? ax * wy : 0.0f;
        const float w11 = (vx1 && vy1) ? wx * wy : 0.0f;
        const int xc0 = min(max(ix, 0), NPIX - 1);
        const int xc1 = min(max(ix + 1, 0), NPIX - 1);
        const int yc0 = min(max(iy, 0), NPIX - 1);
        const int yc1 = min(max(iy + 1, 0), NPIX - 1);
        const int i00 = (yc0 << 9) + xc0, i01 = (yc0 << 9) + xc1;
        const int i10 = (yc1 << 9) + xc0, i11 = (yc1 << 9) + xc1;
#pragma unroll
        for (int b = 0; b < NBATCH; ++b) {
            const float* img = image + (size_t)b * (NPIX * NPIX);
            acc[b] = fmaf(w00, img[i00], fmaf(w01, img[i01],
                     fmaf(w10, img[i10], fmaf(w11, img[i11], acc[b]))));
        }
    }
#pragma unroll
    for (int b = 0; b < NBATCH; ++b)
        out[((size_t)b * NVIEW + v) * NDET + d] = acc[b] * DT;
}

extern "C" void kernel_launch(void* const* d_in, const int* in_sizes, int n_in,
                              void* d_out, int out_size, void* d_ws, size_t ws_size,
                              hipStream_t stream) {
    const float* image = (const float*)d_in[0];
    const float* views = (const float*)d_in[1];
    float* out = (float*)d_out;

    const size_t packed_bytes = (size_t)NPIX * NPIX * sizeof(int4);
    if (ws_size >= packed_bytes && d_ws != nullptr) {
        int4* packed = (int4*)d_ws;
        repack_kernel<<<dim3((NPIX * NPIX) / 256), dim3(256), 0, stream>>>(image, packed);
        projector_kernel<<<dim3(NDET / 64, NVIEW), dim3(256), 0, stream>>>(
            packed, views, out);
    } else {
        projector_kernel_fallback<<<dim3(NDET / 256, NVIEW), dim3(256), 0, stream>>>(image, views, out);
    }
}

// Round 12
// 256.499 us; speedup vs baseline: 46.4268x; 1.1021x over previous
//
#include <hip/hip_runtime.h>

#define NPIX   512
#define NDET   768
#define NSAMP  768
#define NVIEW  360
#define NBATCH 8

// u4 dot8: acc += sum_k nib_k(a)*nib_k(b).  Builtin gated in DEVICE pass only
// (R7 lesson: host-pass __has_builtin is false for amdgcn builtins).
__device__ __forceinline__ int udot8(int a, int b, int acc) {
#if defined(__HIP_DEVICE_COMPILE__) && defined(__has_builtin)
#if __has_builtin(__builtin_amdgcn_udot8)
    return (int)__builtin_amdgcn_udot8((unsigned)a, (unsigned)b, (unsigned)acc, false);
#define UDOT8_DONE 1
#endif
#endif
#ifndef UDOT8_DONE
#pragma unroll
    for (int k = 0; k < 8; ++k)
        acc += ((a >> (4 * k)) & 15) * ((b >> (4 * k)) & 15);
    return acc;
#endif
}

// ---------------------------------------------------------------------------
// Repack image [8,512,512] fp32 -> u4 quad-pack, NIBBLE-INTERLEAVED batches:
//   pixel (y,x), dword d (d=0..3) = batches {2d (even nibbles), 2d+1 (odd)}:
//     nibble 2c   = round(15*v[2d  ]) at corner c
//     nibble 2c+1 = round(15*v[2d+1]) at corner c
//   corners c: 0=(x,y) 1=(x+1,y) 2=(x,y+1) 3=(x+1,y+1)   (clamped)
// ONE dwordx4 gather = all 4 bilinear corners x all 8 batches.
// Footprint 4 MB -> L2-resident (R4 lesson: 8 MB thrashes).
// ---------------------------------------------------------------------------
__global__ __launch_bounds__(256) void repack_kernel(
    const float* __restrict__ image,    // [8, 512, 512]
    int4* __restrict__ packed)          // [512*512]
{
    const int idx = blockIdx.x * blockDim.x + threadIdx.x;  // (y<<9)|x
    if (idx >= NPIX * NPIX) return;
    const int x  = idx & (NPIX - 1);
    const int y  = idx >> 9;
    const int x1 = min(x + 1, NPIX - 1);
    const int y1 = min(y + 1, NPIX - 1);
    const int c0 = (y << 9) + x, c1 = (y << 9) + x1;
    const int c2 = (y1 << 9) + x, c3 = (y1 << 9) + x1;
    int w[4];
#pragma unroll
    for (int d = 0; d < 4; ++d) {
        const float* imgA = image + (size_t)(2 * d)     * (NPIX * NPIX);
        const float* imgB = image + (size_t)(2 * d + 1) * (NPIX * NPIX);
        const int a0 = (int)(imgA[c0] * 15.0f + 0.5f);
        const int a1 = (int)(imgA[c1] * 15.0f + 0.5f);
        const int a2 = (int)(imgA[c2] * 15.0f + 0.5f);
        const int a3 = (int)(imgA[c3] * 15.0f + 0.5f);
        const int b0 = (int)(imgB[c0] * 15.0f + 0.5f);
        const int b1 = (int)(imgB[c1] * 15.0f + 0.5f);
        const int b2 = (int)(imgB[c2] * 15.0f + 0.5f);
        const int b3 = (int)(imgB[c3] * 15.0f + 0.5f);
        w[d] = a0 | (b0 << 4) | (a1 << 8)  | (b1 << 12)
             | (a2 << 16) | (b2 << 20) | (a3 << 24) | (b3 << 28);
    }
    packed[idx] = make_int4(w[0], w[1], w[2], w[3]);
}

// R12: u4 DITHERED weights (8 udot8/sample, half of R10's 16).
// wA has weight[c] in the LOW nibble of byte c (hits even-batch nibbles);
// wA<<4 hits odd-batch nibbles.
// floor(15*w + dither) with shared per-sample dither is UNBIASED for every w
// (fixes R9: axis-aligned rays have constant w -> correlated rounding error).
__device__ __forceinline__ void acc_quad_u4(const int4 q, const int wA,
                                            int acc[NBATCH]) {
    const int wB = wA << 4;
    acc[0] = udot8(q.x, wA, acc[0]);
    acc[1] = udot8(q.x, wB, acc[1]);
    acc[2] = udot8(q.y, wA, acc[2]);
    acc[3] = udot8(q.y, wB, acc[3]);
    acc[4] = udot8(q.z, wA, acc[4]);
    acc[5] = udot8(q.z, wB, acc[5]);
    acc[6] = udot8(q.w, wA, acc[6]);
    acc[7] = udot8(q.w, wB, acc[7]);
}

// byte-pack 4 weights quantized to u4 via floor(15*w + dith); (int) cast is
// trunc = floor for non-negative args.
__device__ __forceinline__ int pack_w4d(float w00, float w01, float w10,
                                        float w11, float dith) {
    const int u0 = (int)fmaf(w00, 15.0f, dith);
    const int u1 = (int)fmaf(w01, 15.0f, dith);
    const int u2 = (int)fmaf(w10, 15.0f, dith);
    const int u3 = (int)fmaf(w11, 15.0f, dith);
    return u0 | (u1 << 8) | (u2 << 16) | (u3 << 24);
}

__device__ __forceinline__ float dither_of(float sf) {
    const float t = sf * 0.61803398875f;
    return t - floorf(t);
}

// ---------------------------------------------------------------------------
// Main projector. Wave = 16 detectors x 4 sample-offsets (R6 patch locality).
// Per sample: ONE dwordx4 gather + 8 v_dot8 (dithered u4 weights).
// Interior loop software-pipelined (R11).
// ---------------------------------------------------------------------------
__global__ __launch_bounds__(256) void projector_kernel(
    const int4* __restrict__ pk,        // [512*512] u4 quad-pack interleaved
    const float* __restrict__ views,    // [360]
    float* __restrict__ out)            // [8, 360, 768]
{
    const int lane    = threadIdx.x & 63;
    const int wave    = threadIdx.x >> 6;
    const int detlane = lane & 15;
    const int soff    = lane >> 4;
    const int d = blockIdx.x * 64 + wave * 16 + detlane;
    const int v = blockIdx.y;

    const float PIX   = 0.7433f;
    const float ISO   = 595.0f;
    const float SDD_  = 595.0f + 490.6f;
    const float DGAM  = 1.2858f / SDD_;
    const float FOV   = 512.0f * 0.7433f * 0.70710678f;
    const float T0    = ISO - FOV;
    const float DT    = 2.0f * FOV / (float)NSAMP;

    const float beta  = views[v];
    const float gamma = ((float)d - 0.5f * (float)(NDET - 1)) * DGAM;
    const float sx = ISO * cosf(beta);
    const float sy = ISO * sinf(beta);
    const float ang = beta + 3.14159265358979f + gamma;
    const float gx = cosf(ang) / PIX;
    const float gy = sinf(ang) / PIX;
    const float cx = sx / PIX + 0.5f * (float)(NPIX - 1);
    const float cy = sy / PIX + 0.5f * (float)(NPIX - 1);

    // ---- clip sample range to padded image box (pad 3 px; outside = 0) ----
    const float PLO = -3.0f, PHI = (float)NPIX + 2.0f;
    float lo = T0 + 0.5f * DT;
    float hi = T0 + ((float)NSAMP - 0.5f) * DT;
    if (fabsf(gx) > 1e-8f) {
        float ta = (PLO - cx) / gx, tb = (PHI - cx) / gx;
        lo = fmaxf(lo, fminf(ta, tb));
        hi = fminf(hi, fmaxf(ta, tb));
    } else if (cx < PLO || cx > PHI) {
        hi = lo - 1.0f;
    }
    if (fabsf(gy) > 1e-8f) {
        float ta = (PLO - cy) / gy, tb = (PHI - cy) / gy;
        lo = fmaxf(lo, fminf(ta, tb));
        hi = fminf(hi, fmaxf(ta, tb));
    } else if (cy < PLO || cy > PHI) {
        hi = lo - 1.0f;
    }

    int s_begin = 0, s_end = 0;
    if (hi >= lo) {
        s_begin = max(0, (int)floorf((lo - T0) / DT - 0.5f));
        s_end   = min(NSAMP, (int)ceilf((hi - T0) / DT - 0.5f) + 1);
    }

    // ---- interior range: strictly inside [0.01, 510.99]^2 (no clamping) ---
    const float XLO = 0.01f, XHI = 510.99f;
    float ilo = lo, ihi = hi;
    if (fabsf(gx) > 1e-8f) {
        float ta = (XLO - cx) / gx, tb = (XHI - cx) / gx;
        ilo = fmaxf(ilo, fminf(ta, tb));
        ihi = fminf(ihi, fmaxf(ta, tb));
    } else if (cx < XLO || cx > XHI) {
        ihi = ilo - 1.0f;
    }
    if (fabsf(gy) > 1e-8f) {
        float ta = (XLO - cy) / gy, tb = (XHI - cy) / gy;
        ilo = fmaxf(ilo, fminf(ta, tb));
        ihi = fminf(ihi, fmaxf(ta, tb));
    } else if (cy < XLO || cy > XHI) {
        ihi = ilo - 1.0f;
    }

    int ib = s_begin, ie = s_begin;
    if (ihi >= ilo) {
        ib = max(s_begin, (int)ceilf ((ilo - T0) / DT - 0.5f));
        ie = min(s_end,   (int)floorf((ihi - T0) / DT - 0.5f) + 1);
        if (ie < ib) { ib = s_begin; ie = s_begin; }
    }

    const float fxs = gx * DT;
    const float fys = gy * DT;
    const float fx0 = fmaf(gx, T0 + 0.5f * DT, cx);
    const float fy0 = fmaf(gy, T0 + 0.5f * DT, cy);

    int acc[NBATCH];
#pragma unroll
    for (int b = 0; b < NBATCH; ++b) acc[b] = 0;

    int s = s_begin + soff;          // this thread's samples: step 4

    // ---------------- border loop 1: s < ib --------------------------------
    for (; s < ib; s += 4) {
        const float sf = (float)s;
        const float fx = fmaf(fxs, sf, fx0);
        const float fy = fmaf(fys, sf, fy0);
        const float x0f = floorf(fx), y0f = floorf(fy);
        const float wx = fx - x0f, wy = fy - y0f;
        const int ix = (int)x0f, iy = (int)y0f;
        const float ax = 1.0f - wx, ay = 1.0f - wy;
        const bool vx0 = (unsigned)ix       < (unsigned)NPIX;
        const bool vx1 = (unsigned)(ix + 1) < (unsigned)NPIX;
        const bool vy0 = (unsigned)iy       < (unsigned)NPIX;
        const bool vy1 = (unsigned)(iy + 1) < (unsigned)NPIX;
        float w00 = (vx0 && vy0) ? ax * ay : 0.0f;
        float w01 = (vx1 && vy0) ? wx * ay : 0.0f;
        float w10 = (vx0 && vy1) ? ax * wy : 0.0f;
        float w11 = (vx1 && vy1) ? wx * wy : 0.0f;
        const bool xneg = (ix < 0);
        float s00 = xneg ? w01 : w00, s01 = xneg ? 0.0f : w01;
        float s10 = xneg ? w11 : w10, s11 = xneg ? 0.0f : w11;
        const bool yneg = (iy < 0);
        const float t00 = yneg ? s10 : s00, t10 = yneg ? 0.0f : s10;
        const float t01 = yneg ? s11 : s01, t11 = yneg ? 0.0f : s11;
        const int px = min(max(ix, 0), NPIX - 1);
        const int py = min(max(iy, 0), NPIX - 1);
        acc_quad_u4(pk[(py << 9) + px],
                    pack_w4d(t00, t01, t10, t11, dither_of(sf)), acc);
    }

    // ------- interior loop: s < ie, software-pipelined (prefetch q) --------
    if (s < ie) {
        float sfc = (float)s;
        float fx = fmaf(fxs, sfc, fx0);
        float fy = fmaf(fys, sfc, fy0);
        float x0f = floorf(fx), y0f = floorf(fy);
        float wxc = fx - x0f, wyc = fy - y0f;
        int4 q = pk[((int)y0f << 9) + (int)x0f];
        int sn = s + 4;
        for (; sn < ie; sn += 4) {
            // issue NEXT gather first (no dependency on current consume)
            const float sf2 = (float)sn;
            const float fx2 = fmaf(fxs, sf2, fx0);
            const float fy2 = fmaf(fys, sf2, fy0);
            const float x2f = floorf(fx2), y2f = floorf(fy2);
            const int4 q2 = pk[((int)y2f << 9) + (int)x2f];
            // consume CURRENT sample
            const float ax = 1.0f - wxc, ay = 1.0f - wyc;
            acc_quad_u4(q, pack_w4d(ax * ay, wxc * ay, ax * wyc, wxc * wyc,
                                    dither_of(sfc)), acc);
            // rotate
            q = q2; wxc = fx2 - x2f; wyc = fy2 - y2f; sfc = sf2;
        }
        // epilogue: consume last pending sample
        const float ax = 1.0f - wxc, ay = 1.0f - wyc;
        acc_quad_u4(q, pack_w4d(ax * ay, wxc * ay, ax * wyc, wxc * wyc,
                                dither_of(sfc)), acc);
        s = sn;
    }

    // ---------------- border loop 2: s < s_end -----------------------------
    for (; s < s_end; s += 4) {
        const float sf = (float)s;
        const float fx = fmaf(fxs, sf, fx0);
        const float fy = fmaf(fys, sf, fy0);
        const float x0f = floorf(fx), y0f = floorf(fy);
        const float wx = fx - x0f, wy = fy - y0f;
        const int ix = (int)x0f, iy = (int)y0f;
        const float ax = 1.0f - wx, ay = 1.0f - wy;
        const bool vx0 = (unsigned)ix       < (unsigned)NPIX;
        const bool vx1 = (unsigned)(ix + 1) < (unsigned)NPIX;
        const bool vy0 = (unsigned)iy       < (unsigned)NPIX;
        const bool vy1 = (unsigned)(iy + 1) < (unsigned)NPIX;
        float w00 = (vx0 && vy0) ? ax * ay : 0.0f;
        float w01 = (vx1 && vy0) ? wx * ay : 0.0f;
        float w10 = (vx0 && vy1) ? ax * wy : 0.0f;
        float w11 = (vx1 && vy1) ? wx * wy : 0.0f;
        const bool xneg = (ix < 0);
        float s00 = xneg ? w01 : w00, s01 = xneg ? 0.0f : w01;
        float s10 = xneg ? w11 : w10, s11 = xneg ? 0.0f : w11;
        const bool yneg = (iy < 0);
        const float t00 = yneg ? s10 : s00, t10 = yneg ? 0.0f : s10;
        const float t01 = yneg ? s11 : s01, t11 = yneg ? 0.0f : s11;
        const int px = min(max(ix, 0), NPIX - 1);
        const int py = min(max(iy, 0), NPIX - 1);
        acc_quad_u4(pk[(py << 9) + px],
                    pack_w4d(t00, t01, t10, t11, dither_of(sf)), acc);
    }

    // ---- reduce the 4 soff partials, scale, store -------------------------
#pragma unroll
    for (int b = 0; b < NBATCH; ++b) {
        int a = acc[b];
        a += __shfl_xor(a, 16, 64);
        a += __shfl_xor(a, 32, 64);
        acc[b] = a;
    }

    if (soff == 0) {
        const float SCALE = DT * (1.0f / (15.0f * 15.0f));
#pragma unroll
        for (int b = 0; b < NBATCH; ++b)
            out[((size_t)b * NVIEW + v) * NDET + d] = (float)acc[b] * SCALE;
    }
}

// ---------------------------------------------------------------------------
// Fallback (original layout, fp32 scalar loads) — only if ws too small.
// ---------------------------------------------------------------------------
__global__ __launch_bounds__(256) void projector_kernel_fallback(
    const float* __restrict__ image, const float* __restrict__ views,
    float* __restrict__ out)
{
    const int d = blockIdx.x * blockDim.x + threadIdx.x;
    const int v = blockIdx.y;
    if (d >= NDET) return;

    const float PIX = 0.7433f, ISO = 595.0f;
    const float SDD_ = 595.0f + 490.6f;
    const float DGAM = 1.2858f / SDD_;
    const float FOV  = 512.0f * 0.7433f * 0.70710678f;
    const float T0   = ISO - FOV;
    const float DT   = 2.0f * FOV / (float)NSAMP;

    const float beta  = views[v];
    const float gamma = ((float)d - 0.5f * (float)(NDET - 1)) * DGAM;
    const float sx = ISO * cosf(beta), sy = ISO * sinf(beta);
    const float ang = beta + 3.14159265358979f + gamma;
    const float gx = cosf(ang) / PIX, gy = sinf(ang) / PIX;
    const float cx = sx / PIX + 0.5f * (float)(NPIX - 1);
    const float cy = sy / PIX + 0.5f * (float)(NPIX - 1);

    float acc[NBATCH];
#pragma unroll
    for (int b = 0; b < NBATCH; ++b) acc[b] = 0.0f;

    for (int s = 0; s < NSAMP; ++s) {
        const float t  = fmaf((float)s + 0.5f, DT, T0);
        const float fx = fmaf(gx, t, cx);
        const float fy = fmaf(gy, t, cy);
        const float x0f = floorf(fx), y0f = floorf(fy);
        const float wx = fx - x0f, wy = fy - y0f;
        const int ix = (int)x0f, iy = (int)y0f;
        const float ax = 1.0f - wx, ay = 1.0f - wy;
        const bool vx0 = (unsigned)ix < (unsigned)NPIX;
        const bool vx1 = (unsigned)(ix + 1) < (unsigned)NPIX;
        const bool vy0 = (unsigned)iy < (unsigned)NPIX;
        const bool vy1 = (unsigned)(iy + 1) < (unsigned)NPIX;
        const float w00 = (vx0 && vy0) ? ax * ay : 0.0f;
        const float w01 = (vx1 && vy0) ? wx * ay : 0.0f;
        const float w10 = (vx0 && vy1) ? ax * wy : 0.0f;
        const float w11 = (vx1 && vy1) ? wx * wy : 0.0f;
        const int xc0 = min(max(ix, 0), NPIX - 1);
        const int xc1 = min(max(ix + 1, 0), NPIX - 1);
        const int yc0 = min(max(iy, 0), NPIX - 1);
        const int yc1 = min(max(iy + 1, 0), NPIX - 1);
        const int i00 = (yc0 << 9) + xc0, i01 = (yc0 << 9) + xc1;
        const int i10 = (yc1 << 9) + xc0, i11 = (yc1 << 9) + xc1;
#pragma unroll
        for (int b = 0; b < NBATCH; ++b) {
            const float* img = image + (size_t)b * (NPIX * NPIX);
            acc[b] = fmaf(w00, img[i00], fmaf(w01, img[i01],
                     fmaf(w10, img[i10], fmaf(w11, img[i11], acc[b]))));
        }
    }
#pragma unroll
    for (int b = 0; b < NBATCH; ++b)
        out[((size_t)b * NVIEW + v) * NDET + d] = acc[b] * DT;
}

extern "C" void kernel_launch(void* const* d_in, const int* in_sizes, int n_in,
                              void* d_out, int out_size, void* d_ws, size_t ws_size,
                              hipStream_t stream) {
    const float* image = (const float*)d_in[0];
    const float* views = (const float*)d_in[1];
    float* out = (float*)d_out;

    const size_t packed_bytes = (size_t)NPIX * NPIX * sizeof(int4);
    if (ws_size >= packed_bytes && d_ws != nullptr) {
        int4* packed = (int4*)d_ws;
        repack_kernel<<<dim3((NPIX * NPIX) / 256), dim3(256), 0, stream>>>(image, packed);
        projector_kernel<<<dim3(NDET / 64, NVIEW), dim3(256), 0, stream>>>(
            packed, views, out);
    } else {
        projector_kernel_fallback<<<dim3(NDET / 256, NVIEW), dim3(256), 0, stream>>>(image, views, out);
    }
}

// Round 13
// 223.787 us; speedup vs baseline: 53.2132x; 1.1462x over previous
//
#include <hip/hip_runtime.h>

#define NPIX   512
#define NDET   768
#define NSAMP  768
#define NVIEW  360
#define NBATCH 8

// u4 dot8: acc += sum_k nib_k(a)*nib_k(b).  Builtin gated in DEVICE pass only
// (R7 lesson: host-pass __has_builtin is false for amdgcn builtins).
__device__ __forceinline__ int udot8(int a, int b, int acc) {
#if defined(__HIP_DEVICE_COMPILE__) && defined(__has_builtin)
#if __has_builtin(__builtin_amdgcn_udot8)
    return (int)__builtin_amdgcn_udot8((unsigned)a, (unsigned)b, (unsigned)acc, false);
#define UDOT8_DONE 1
#endif
#endif
#ifndef UDOT8_DONE
#pragma unroll
    for (int k = 0; k < 8; ++k)
        acc += ((a >> (4 * k)) & 15) * ((b >> (4 * k)) & 15);
    return acc;
#endif
}

__device__ __forceinline__ float fracf(float x) { return x - floorf(x); }

// ---------------------------------------------------------------------------
// Repack image [8,512,512] fp32 -> u4 quad-pack, NIBBLE-INTERLEAVED batches:
//   pixel (y,x), dword d (d=0..3) = batches {2d (even nibbles), 2d+1 (odd)}:
//     nibble 2c   = round(15*v[2d  ]) at corner c
//     nibble 2c+1 = round(15*v[2d+1]) at corner c
//   corners c: 0=(x,y) 1=(x+1,y) 2=(x,y+1) 3=(x+1,y+1)   (clamped)
// ONE dwordx4 gather = all 4 bilinear corners x all 8 batches.
// Footprint 4 MB -> L2-resident (R4 lesson: 8 MB thrashes).
// ---------------------------------------------------------------------------
__global__ __launch_bounds__(256) void repack_kernel(
    const float* __restrict__ image,    // [8, 512, 512]
    int4* __restrict__ packed)          // [512*512]
{
    const int idx = blockIdx.x * blockDim.x + threadIdx.x;  // (y<<9)|x
    if (idx >= NPIX * NPIX) return;
    const int x  = idx & (NPIX - 1);
    const int y  = idx >> 9;
    const int x1 = min(x + 1, NPIX - 1);
    const int y1 = min(y + 1, NPIX - 1);
    const int c0 = (y << 9) + x, c1 = (y << 9) + x1;
    const int c2 = (y1 << 9) + x, c3 = (y1 << 9) + x1;
    int w[4];
#pragma unroll
    for (int d = 0; d < 4; ++d) {
        const float* imgA = image + (size_t)(2 * d)     * (NPIX * NPIX);
        const float* imgB = image + (size_t)(2 * d + 1) * (NPIX * NPIX);
        const int a0 = (int)(imgA[c0] * 15.0f + 0.5f);
        const int a1 = (int)(imgA[c1] * 15.0f + 0.5f);
        const int a2 = (int)(imgA[c2] * 15.0f + 0.5f);
        const int a3 = (int)(imgA[c3] * 15.0f + 0.5f);
        const int b0 = (int)(imgB[c0] * 15.0f + 0.5f);
        const int b1 = (int)(imgB[c1] * 15.0f + 0.5f);
        const int b2 = (int)(imgB[c2] * 15.0f + 0.5f);
        const int b3 = (int)(imgB[c3] * 15.0f + 0.5f);
        w[d] = a0 | (b0 << 4) | (a1 << 8)  | (b1 << 12)
             | (a2 << 16) | (b2 << 20) | (a3 << 24) | (b3 << 28);
    }
    packed[idx] = make_int4(w[0], w[1], w[2], w[3]);
}

// u4 DITHERED weights (8 udot8/sample).  wA: weight[c] in LOW nibble of
// byte c (even-batch nibbles); wA<<4 hits odd-batch nibbles.
// floor(15*w + dither) with shared per-sample dither is UNBIASED for every w
// (R9 lesson: constant-w axis-aligned rays need it).
__device__ __forceinline__ void acc_quad_u4(const int4 q, const int wA,
                                            int acc[NBATCH]) {
    const int wB = wA << 4;
    acc[0] = udot8(q.x, wA, acc[0]);
    acc[1] = udot8(q.x, wB, acc[1]);
    acc[2] = udot8(q.y, wA, acc[2]);
    acc[3] = udot8(q.y, wB, acc[3]);
    acc[4] = udot8(q.z, wA, acc[4]);
    acc[5] = udot8(q.z, wB, acc[5]);
    acc[6] = udot8(q.w, wA, acc[6]);
    acc[7] = udot8(q.w, wB, acc[7]);
}

// R13 trimmed consume: pre-scaled ay15/wy15 -> 4 direct fmaf (saves 4 muls)
__device__ __forceinline__ void consume(const int4 q, float wx, float wy,
                                        float dith, int acc[NBATCH]) {
    const float ax   = 1.0f - wx;
    const float ay15 = (1.0f - wy) * 15.0f;
    const float wy15 = wy * 15.0f;
    const int u0 = (int)fmaf(ax, ay15, dith);
    const int u1 = (int)fmaf(wx, ay15, dith);
    const int u2 = (int)fmaf(ax, wy15, dith);
    const int u3 = (int)fmaf(wx, wy15, dith);
    acc_quad_u4(q, u0 | (u1 << 8) | (u2 << 16) | (u3 << 24), acc);
}

__device__ __forceinline__ int pack_w4d(float w00, float w01, float w10,
                                        float w11, float dith) {
    const int u0 = (int)fmaf(w00, 15.0f, dith);
    const int u1 = (int)fmaf(w01, 15.0f, dith);
    const int u2 = (int)fmaf(w10, 15.0f, dith);
    const int u3 = (int)fmaf(w11, 15.0f, dith);
    return u0 | (u1 << 8) | (u2 << 16) | (u3 << 24);
}

__device__ __forceinline__ float dither_of(float sf) {
    return fracf(sf * 0.61803398875f);
}

// ---------------------------------------------------------------------------
// Main projector. Wave = 16 detectors x 4 sample-offsets (R6 patch locality).
// Per sample: ONE dwordx4 gather + 8 v_dot8 (dithered u4 weights).
// R13: depth-2 software pipeline (two gathers in flight), incremental dither.
// ---------------------------------------------------------------------------
__global__ __launch_bounds__(256) void projector_kernel(
    const int4* __restrict__ pk,        // [512*512] u4 quad-pack interleaved
    const float* __restrict__ views,    // [360]
    float* __restrict__ out)            // [8, 360, 768]
{
    const int lane    = threadIdx.x & 63;
    const int wave    = threadIdx.x >> 6;
    const int detlane = lane & 15;
    const int soff    = lane >> 4;
    const int d = blockIdx.x * 64 + wave * 16 + detlane;
    const int v = blockIdx.y;

    const float PIX   = 0.7433f;
    const float ISO   = 595.0f;
    const float SDD_  = 595.0f + 490.6f;
    const float DGAM  = 1.2858f / SDD_;
    const float FOV   = 512.0f * 0.7433f * 0.70710678f;
    const float T0    = ISO - FOV;
    const float DT    = 2.0f * FOV / (float)NSAMP;

    const float beta  = views[v];
    const float gamma = ((float)d - 0.5f * (float)(NDET - 1)) * DGAM;
    const float sx = ISO * cosf(beta);
    const float sy = ISO * sinf(beta);
    const float ang = beta + 3.14159265358979f + gamma;
    const float gx = cosf(ang) / PIX;
    const float gy = sinf(ang) / PIX;
    const float cx = sx / PIX + 0.5f * (float)(NPIX - 1);
    const float cy = sy / PIX + 0.5f * (float)(NPIX - 1);

    // ---- clip sample range to image support (contrib 0 outside (-1,512)) --
    const float PLO = -1.0f, PHI = 512.0f;
    float lo = T0 + 0.5f * DT;
    float hi = T0 + ((float)NSAMP - 0.5f) * DT;
    if (fabsf(gx) > 1e-8f) {
        float ta = (PLO - cx) / gx, tb = (PHI - cx) / gx;
        lo = fmaxf(lo, fminf(ta, tb));
        hi = fminf(hi, fmaxf(ta, tb));
    } else if (cx < PLO || cx > PHI) {
        hi = lo - 1.0f;
    }
    if (fabsf(gy) > 1e-8f) {
        float ta = (PLO - cy) / gy, tb = (PHI - cy) / gy;
        lo = fmaxf(lo, fminf(ta, tb));
        hi = fminf(hi, fmaxf(ta, tb));
    } else if (cy < PLO || cy > PHI) {
        hi = lo - 1.0f;
    }

    int s_begin = 0, s_end = 0;
    if (hi >= lo) {
        s_begin = max(0, (int)floorf((lo - T0) / DT - 0.5f));
        s_end   = min(NSAMP, (int)ceilf((hi - T0) / DT - 0.5f) + 1);
    }

    // ---- interior range: strictly inside [0.01, 510.99]^2 (no clamping) ---
    const float XLO = 0.01f, XHI = 510.99f;
    float ilo = lo, ihi = hi;
    if (fabsf(gx) > 1e-8f) {
        float ta = (XLO - cx) / gx, tb = (XHI - cx) / gx;
        ilo = fmaxf(ilo, fminf(ta, tb));
        ihi = fminf(ihi, fmaxf(ta, tb));
    } else if (cx < XLO || cx > XHI) {
        ihi = ilo - 1.0f;
    }
    if (fabsf(gy) > 1e-8f) {
        float ta = (XLO - cy) / gy, tb = (XHI - cy) / gy;
        ilo = fmaxf(ilo, fminf(ta, tb));
        ihi = fminf(ihi, fmaxf(ta, tb));
    } else if (cy < XLO || cy > XHI) {
        ihi = ilo - 1.0f;
    }

    int ib = s_begin, ie = s_begin;
    if (ihi >= ilo) {
        ib = max(s_begin, (int)ceilf ((ilo - T0) / DT - 0.5f));
        ie = min(s_end,   (int)floorf((ihi - T0) / DT - 0.5f) + 1);
        if (ie < ib) { ib = s_begin; ie = s_begin; }
    }

    const float fxs = gx * DT;
    const float fys = gy * DT;
    const float fx0 = fmaf(gx, T0 + 0.5f * DT, cx);
    const float fy0 = fmaf(gy, T0 + 0.5f * DT, cy);

    int acc[NBATCH];
#pragma unroll
    for (int b = 0; b < NBATCH; ++b) acc[b] = 0;

    int s = s_begin + soff;          // this thread's samples: step 4

    // ---------------- border loop 1: s < ib --------------------------------
    for (; s < ib; s += 4) {
        const float sf = (float)s;
        const float fx = fmaf(fxs, sf, fx0);
        const float fy = fmaf(fys, sf, fy0);
        const float x0f = floorf(fx), y0f = floorf(fy);
        const float wx = fx - x0f, wy = fy - y0f;
        const int ix = (int)x0f, iy = (int)y0f;
        const float ax = 1.0f - wx, ay = 1.0f - wy;
        const bool vx0 = (unsigned)ix       < (unsigned)NPIX;
        const bool vx1 = (unsigned)(ix + 1) < (unsigned)NPIX;
        const bool vy0 = (unsigned)iy       < (unsigned)NPIX;
        const bool vy1 = (unsigned)(iy + 1) < (unsigned)NPIX;
        float w00 = (vx0 && vy0) ? ax * ay : 0.0f;
        float w01 = (vx1 && vy0) ? wx * ay : 0.0f;
        float w10 = (vx0 && vy1) ? ax * wy : 0.0f;
        float w11 = (vx1 && vy1) ? wx * wy : 0.0f;
        const bool xneg = (ix < 0);
        float s00 = xneg ? w01 : w00, s01 = xneg ? 0.0f : w01;
        float s10 = xneg ? w11 : w10, s11 = xneg ? 0.0f : w11;
        const bool yneg = (iy < 0);
        const float t00 = yneg ? s10 : s00, t10 = yneg ? 0.0f : s10;
        const float t01 = yneg ? s11 : s01, t11 = yneg ? 0.0f : s11;
        const int px = min(max(ix, 0), NPIX - 1);
        const int py = min(max(iy, 0), NPIX - 1);
        acc_quad_u4(pk[(py << 9) + px],
                    pack_w4d(t00, t01, t10, t11, dither_of(sf)), acc);
    }

    // -------- interior: s < ie, depth-2 pipeline, incremental dither -------
    if (s < ie) {
        const int n = (ie - s + 3) >> 2;        // # interior samples
        const float DSTEP = 0.47213595499f;     // frac(4 * 0.618...)
        float sf = (float)s;
        // state A = sample s
        float dA = dither_of(sf);
        float fxa = fmaf(fxs, sf, fx0), fya = fmaf(fys, sf, fy0);
        float xfa = floorf(fxa), yfa = floorf(fya);
        float wxa = fxa - xfa, wya = fya - yfa;
        int4 qa = pk[((int)yfa << 9) + (int)xfa];
        if (n == 1) {
            consume(qa, wxa, wya, dA, acc);
        } else {
            // state B = sample s+4
            float sfb = sf + 4.0f;
            float dB = fracf(dA + DSTEP);
            float fxb = fmaf(fxs, sfb, fx0), fyb = fmaf(fys, sfb, fy0);
            float xfb = floorf(fxb), yfb = floorf(fyb);
            float wxb = fxb - xfb, wyb = fyb - yfb;
            int4 qb = pk[((int)yfb << 9) + (int)xfb];
            float sfn = sfb + 4.0f;
            float dN = dB;
            for (int k = 2; k < n; ++k, sfn += 4.0f) {
                // prefetch sample k (2 loads always in flight)
                dN = fracf(dN + DSTEP);
                const float fxc = fmaf(fxs, sfn, fx0);
                const float fyc = fmaf(fys, sfn, fy0);
                const float xfc = floorf(fxc), yfc = floorf(fyc);
                const int4 qc = pk[((int)yfc << 9) + (int)xfc];
                // consume oldest
                consume(qa, wxa, wya, dA, acc);
                // rotate
                qa = qb; wxa = wxb; wya = wyb; dA = dB;
                qb = qc; wxb = fxc - xfc; wyb = fyc - yfc; dB = dN;
            }
            consume(qa, wxa, wya, dA, acc);
            consume(qb, wxb, wyb, dB, acc);
        }
        s += n << 2;
    }

    // ---------------- border loop 2: s < s_end -----------------------------
    for (; s < s_end; s += 4) {
        const float sf = (float)s;
        const float fx = fmaf(fxs, sf, fx0);
        const float fy = fmaf(fys, sf, fy0);
        const float x0f = floorf(fx), y0f = floorf(fy);
        const float wx = fx - x0f, wy = fy - y0f;
        const int ix = (int)x0f, iy = (int)y0f;
        const float ax = 1.0f - wx, ay = 1.0f - wy;
        const bool vx0 = (unsigned)ix       < (unsigned)NPIX;
        const bool vx1 = (unsigned)(ix + 1) < (unsigned)NPIX;
        const bool vy0 = (unsigned)iy       < (unsigned)NPIX;
        const bool vy1 = (unsigned)(iy + 1) < (unsigned)NPIX;
        float w00 = (vx0 && vy0) ? ax * ay : 0.0f;
        float w01 = (vx1 && vy0) ? wx * ay : 0.0f;
        float w10 = (vx0 && vy1) ? ax * wy : 0.0f;
        float w11 = (vx1 && vy1) ? wx * wy : 0.0f;
        const bool xneg = (ix < 0);
        float s00 = xneg ? w01 : w00, s01 = xneg ? 0.0f : w01;
        float s10 = xneg ? w11 : w10, s11 = xneg ? 0.0f : w11;
        const bool yneg = (iy < 0);
        const float t00 = yneg ? s10 : s00, t10 = yneg ? 0.0f : s10;
        const float t01 = yneg ? s11 : s01, t11 = yneg ? 0.0f : s11;
        const int px = min(max(ix, 0), NPIX - 1);
        const int py = min(max(iy, 0), NPIX - 1);
        acc_quad_u4(pk[(py << 9) + px],
                    pack_w4d(t00, t01, t10, t11, dither_of(sf)), acc);
    }

    // ---- reduce the 4 soff partials, scale, store -------------------------
#pragma unroll
    for (int b = 0; b < NBATCH; ++b) {
        int a = acc[b];
        a += __shfl_xor(a, 16, 64);
        a += __shfl_xor(a, 32, 64);
        acc[b] = a;
    }

    if (soff == 0) {
        const float SCALE = DT * (1.0f / (15.0f * 15.0f));
#pragma unroll
        for (int b = 0; b < NBATCH; ++b)
            out[((size_t)b * NVIEW + v) * NDET + d] = (float)acc[b] * SCALE;
    }
}

// ---------------------------------------------------------------------------
// Fallback (original layout, fp32 scalar loads) — only if ws too small.
// ---------------------------------------------------------------------------
__global__ __launch_bounds__(256) void projector_kernel_fallback(
    const float* __restrict__ image, const float* __restrict__ views,
    float* __restrict__ out)
{
    const int d = blockIdx.x * blockDim.x + threadIdx.x;
    const int v = blockIdx.y;
    if (d >= NDET) return;

    const float PIX = 0.7433f, ISO = 595.0f;
    const float SDD_ = 595.0f + 490.6f;
    const float DGAM = 1.2858f / SDD_;
    const float FOV  = 512.0f * 0.7433f * 0.70710678f;
    const float T0   = ISO - FOV;
    const float DT   = 2.0f * FOV / (float)NSAMP;

    const float beta  = views[v];
    const float gamma = ((float)d - 0.5f * (float)(NDET - 1)) * DGAM;
    const float sx = ISO * cosf(beta), sy = ISO * sinf(beta);
    const float ang = beta + 3.14159265358979f + gamma;
    const float gx = cosf(ang) / PIX, gy = sinf(ang) / PIX;
    const float cx = sx / PIX + 0.5f * (float)(NPIX - 1);
    const float cy = sy / PIX + 0.5f * (float)(NPIX - 1);

    float acc[NBATCH];
#pragma unroll
    for (int b = 0; b < NBATCH; ++b) acc[b] = 0.0f;

    for (int s = 0; s < NSAMP; ++s) {
        const float t  = fmaf((float)s + 0.5f, DT, T0);
        const float fx = fmaf(gx, t, cx);
        const float fy = fmaf(gy, t, cy);
        const float x0f = floorf(fx), y0f = floorf(fy);
        const float wx = fx - x0f, wy = fy - y0f;
        const int ix = (int)x0f, iy = (int)y0f;
        const float ax = 1.0f - wx, ay = 1.0f - wy;
        const bool vx0 = (unsigned)ix < (unsigned)NPIX;
        const bool vx1 = (unsigned)(ix + 1) < (unsigned)NPIX;
        const bool vy0 = (unsigned)iy < (unsigned)NPIX;
        const bool vy1 = (unsigned)(iy + 1) < (unsigned)NPIX;
        const float w00 = (vx0 && vy0) ? ax * ay : 0.0f;
        const float w01 = (vx1 && vy0) ? wx * ay : 0.0f;
        const float w10 = (vx0 && vy1) ? ax * wy : 0.0f;
        const float w11 = (vx1 && vy1) ? wx * wy : 0.0f;
        const int xc0 = min(max(ix, 0), NPIX - 1);
        const int xc1 = min(max(ix + 1, 0), NPIX - 1);
        const int yc0 = min(max(iy, 0), NPIX - 1);
        const int yc1 = min(max(iy + 1, 0), NPIX - 1);
        const int i00 = (yc0 << 9) + xc0, i01 = (yc0 << 9) + xc1;
        const int i10 = (yc1 << 9) + xc0, i11 = (yc1 << 9) + xc1;
#pragma unroll
        for (int b = 0; b < NBATCH; ++b) {
            const float* img = image + (size_t)b * (NPIX * NPIX);
            acc[b] = fmaf(w00, img[i00], fmaf(w01, img[i01],
                     fmaf(w10, img[i10], fmaf(w11, img[i11], acc[b]))));
        }
    }
#pragma unroll
    for (int b = 0; b < NBATCH; ++b)
        out[((size_t)b * NVIEW + v) * NDET + d] = acc[b] * DT;
}

extern "C" void kernel_launch(void* const* d_in, const int* in_sizes, int n_in,
                              void* d_out, int out_size, void* d_ws, size_t ws_size,
                              hipStream_t stream) {
    const float* image = (const float*)d_in[0];
    const float* views = (const float*)d_in[1];
    float* out = (float*)d_out;

    const size_t packed_bytes = (size_t)NPIX * NPIX * sizeof(int4);
    if (ws_size >= packed_bytes && d_ws != nullptr) {
        int4* packed = (int4*)d_ws;
        repack_kernel<<<dim3((NPIX * NPIX) / 256), dim3(256), 0, stream>>>(image, packed);
        projector_kernel<<<dim3(NDET / 64, NVIEW), dim3(256), 0, stream>>>(
            packed, views, out);
    } else {
        projector_kernel_fallback<<<dim3(NDET / 256, NVIEW), dim3(256), 0, stream>>>(image, views, out);
    }
}

// Round 14
// 211.441 us; speedup vs baseline: 56.3203x; 1.0584x over previous
//
#include <hip/hip_runtime.h>

#define NPIX   512
#define NDET   768
#define NSAMP  768
#define NVIEW  360
#define NBATCH 8

// u4 dot8: acc += sum_k nib_k(a)*nib_k(b).  Builtin gated in DEVICE pass only
// (R7 lesson: host-pass __has_builtin is false for amdgcn builtins).
__device__ __forceinline__ int udot8(int a, int b, int acc) {
#if defined(__HIP_DEVICE_COMPILE__) && defined(__has_builtin)
#if __has_builtin(__builtin_amdgcn_udot8)
    return (int)__builtin_amdgcn_udot8((unsigned)a, (unsigned)b, (unsigned)acc, false);
#define UDOT8_DONE 1
#endif
#endif
#ifndef UDOT8_DONE
#pragma unroll
    for (int k = 0; k < 8; ++k)
        acc += ((a >> (4 * k)) & 15) * ((b >> (4 * k)) & 15);
    return acc;
#endif
}

__device__ __forceinline__ float fracf(float x) { return x - floorf(x); }

// ---------------------------------------------------------------------------
// Repack image [8,512,512] fp32 -> u4 quad-pack, NIBBLE-INTERLEAVED batches:
//   pixel (y,x), dword d (d=0..3) = batches {2d (even nibbles), 2d+1 (odd)}:
//     nibble 2c   = round(15*v[2d  ]) at corner c
//     nibble 2c+1 = round(15*v[2d+1]) at corner c
//   corners c: 0=(x,y) 1=(x+1,y) 2=(x,y+1) 3=(x+1,y+1)   (clamped)
// ONE dwordx4 gather = all 4 bilinear corners x all 8 batches.
// Footprint 4 MB -> L2-resident (R4 lesson: 8 MB thrashes).
// ---------------------------------------------------------------------------
__global__ __launch_bounds__(256) void repack_kernel(
    const float* __restrict__ image,    // [8, 512, 512]
    int4* __restrict__ packed)          // [512*512]
{
    const int idx = blockIdx.x * blockDim.x + threadIdx.x;  // (y<<9)|x
    if (idx >= NPIX * NPIX) return;
    const int x  = idx & (NPIX - 1);
    const int y  = idx >> 9;
    const int x1 = min(x + 1, NPIX - 1);
    const int y1 = min(y + 1, NPIX - 1);
    const int c0 = (y << 9) + x, c1 = (y << 9) + x1;
    const int c2 = (y1 << 9) + x, c3 = (y1 << 9) + x1;
    int w[4];
#pragma unroll
    for (int d = 0; d < 4; ++d) {
        const float* imgA = image + (size_t)(2 * d)     * (NPIX * NPIX);
        const float* imgB = image + (size_t)(2 * d + 1) * (NPIX * NPIX);
        const int a0 = (int)(imgA[c0] * 15.0f + 0.5f);
        const int a1 = (int)(imgA[c1] * 15.0f + 0.5f);
        const int a2 = (int)(imgA[c2] * 15.0f + 0.5f);
        const int a3 = (int)(imgA[c3] * 15.0f + 0.5f);
        const int b0 = (int)(imgB[c0] * 15.0f + 0.5f);
        const int b1 = (int)(imgB[c1] * 15.0f + 0.5f);
        const int b2 = (int)(imgB[c2] * 15.0f + 0.5f);
        const int b3 = (int)(imgB[c3] * 15.0f + 0.5f);
        w[d] = a0 | (b0 << 4) | (a1 << 8)  | (b1 << 12)
             | (a2 << 16) | (b2 << 20) | (a3 << 24) | (b3 << 28);
    }
    packed[idx] = make_int4(w[0], w[1], w[2], w[3]);
}

// u4 DITHERED weights (8 udot8/sample).  wA: weight[c] in LOW nibble of
// byte c (even-batch nibbles); wA<<4 hits odd-batch nibbles.
// floor(15*w + dither) with shared per-sample dither is UNBIASED for every w
// (R9 lesson: constant-w axis-aligned rays need it).
__device__ __forceinline__ void acc_quad_u4(const int4 q, const int wA,
                                            int acc[NBATCH]) {
    const int wB = wA << 4;
    acc[0] = udot8(q.x, wA, acc[0]);
    acc[1] = udot8(q.x, wB, acc[1]);
    acc[2] = udot8(q.y, wA, acc[2]);
    acc[3] = udot8(q.y, wB, acc[3]);
    acc[4] = udot8(q.z, wA, acc[4]);
    acc[5] = udot8(q.z, wB, acc[5]);
    acc[6] = udot8(q.w, wA, acc[6]);
    acc[7] = udot8(q.w, wB, acc[7]);
}

// trimmed consume: ay15 via single fmaf; 4 fmaf + 4 cvt + pack
__device__ __forceinline__ void consume(const int4 q, float wx, float wy,
                                        float dith, int acc[NBATCH]) {
    const float ax   = 1.0f - wx;
    const float ay15 = fmaf(wy, -15.0f, 15.0f);
    const float wy15 = wy * 15.0f;
    const int u0 = (int)fmaf(ax, ay15, dith);
    const int u1 = (int)fmaf(wx, ay15, dith);
    const int u2 = (int)fmaf(ax, wy15, dith);
    const int u3 = (int)fmaf(wx, wy15, dith);
    acc_quad_u4(q, u0 | (u1 << 8) | (u2 << 16) | (u3 << 24), acc);
}

__device__ __forceinline__ int pack_w4d(float w00, float w01, float w10,
                                        float w11, float dith) {
    const int u0 = (int)fmaf(w00, 15.0f, dith);
    const int u1 = (int)fmaf(w01, 15.0f, dith);
    const int u2 = (int)fmaf(w10, 15.0f, dith);
    const int u3 = (int)fmaf(w11, 15.0f, dith);
    return u0 | (u1 << 8) | (u2 << 16) | (u3 << 24);
}

__device__ __forceinline__ float dither_of(float sf) {
    return fracf(sf * 0.61803398875f);
}

// R14: slot refill — advance coords incrementally (8 s-units per slot-load),
// advance dither incrementally, load DIRECTLY into the slot registers (the
// slot was freed by the preceding consume -> no rotation v_movs).
__device__ __forceinline__ void load_slot(const int4* __restrict__ pk,
                                          float fxs8, float fys8,
                                          float& fx, float& fy, float& dd,
                                          int4& q, float& wx, float& wy) {
    const float DSTEP8 = 0.94427191f;       // frac(8 * 0.618034)
    fx += fxs8; fy += fys8;
    dd = fracf(dd + DSTEP8);
    const float xf = floorf(fx), yf = floorf(fy);
    q = pk[(int)fmaf(yf, 512.0f, xf)];      // exact: < 2^18
    wx = fx - xf; wy = fy - yf;
}

// ---------------------------------------------------------------------------
// Main projector. Wave = 16 detectors x 4 sample-offsets (R6 patch locality).
// Per sample: ONE dwordx4 gather + 8 v_dot8 (dithered u4 weights).
// R14: move-free unroll-2 pipeline (consume A; refill A; consume B; refill B).
// ---------------------------------------------------------------------------
__global__ __launch_bounds__(256) void projector_kernel(
    const int4* __restrict__ pk,        // [512*512] u4 quad-pack interleaved
    const float* __restrict__ views,    // [360]
    float* __restrict__ out)            // [8, 360, 768]
{
    const int lane    = threadIdx.x & 63;
    const int wave    = threadIdx.x >> 6;
    const int detlane = lane & 15;
    const int soff    = lane >> 4;
    const int d = blockIdx.x * 64 + wave * 16 + detlane;
    const int v = blockIdx.y;

    const float PIX   = 0.7433f;
    const float ISO   = 595.0f;
    const float SDD_  = 595.0f + 490.6f;
    const float DGAM  = 1.2858f / SDD_;
    const float FOV   = 512.0f * 0.7433f * 0.70710678f;
    const float T0    = ISO - FOV;
    const float DT    = 2.0f * FOV / (float)NSAMP;

    const float beta  = views[v];
    const float gamma = ((float)d - 0.5f * (float)(NDET - 1)) * DGAM;
    const float sx = ISO * cosf(beta);
    const float sy = ISO * sinf(beta);
    const float ang = beta + 3.14159265358979f + gamma;
    const float gx = cosf(ang) / PIX;
    const float gy = sinf(ang) / PIX;
    const float cx = sx / PIX + 0.5f * (float)(NPIX - 1);
    const float cy = sy / PIX + 0.5f * (float)(NPIX - 1);

    // ---- clip sample range to image support (contrib 0 outside (-1,512)) --
    const float PLO = -1.0f, PHI = 512.0f;
    float lo = T0 + 0.5f * DT;
    float hi = T0 + ((float)NSAMP - 0.5f) * DT;
    if (fabsf(gx) > 1e-8f) {
        float ta = (PLO - cx) / gx, tb = (PHI - cx) / gx;
        lo = fmaxf(lo, fminf(ta, tb));
        hi = fminf(hi, fmaxf(ta, tb));
    } else if (cx < PLO || cx > PHI) {
        hi = lo - 1.0f;
    }
    if (fabsf(gy) > 1e-8f) {
        float ta = (PLO - cy) / gy, tb = (PHI - cy) / gy;
        lo = fmaxf(lo, fminf(ta, tb));
        hi = fminf(hi, fmaxf(ta, tb));
    } else if (cy < PLO || cy > PHI) {
        hi = lo - 1.0f;
    }

    int s_begin = 0, s_end = 0;
    if (hi >= lo) {
        s_begin = max(0, (int)floorf((lo - T0) / DT - 0.5f));
        s_end   = min(NSAMP, (int)ceilf((hi - T0) / DT - 0.5f) + 1);
    }

    // ---- interior range: strictly inside [0.01, 510.99]^2 (no clamping) ---
    const float XLO = 0.01f, XHI = 510.99f;
    float ilo = lo, ihi = hi;
    if (fabsf(gx) > 1e-8f) {
        float ta = (XLO - cx) / gx, tb = (XHI - cx) / gx;
        ilo = fmaxf(ilo, fminf(ta, tb));
        ihi = fminf(ihi, fmaxf(ta, tb));
    } else if (cx < XLO || cx > XHI) {
        ihi = ilo - 1.0f;
    }
    if (fabsf(gy) > 1e-8f) {
        float ta = (XLO - cy) / gy, tb = (XHI - cy) / gy;
        ilo = fmaxf(ilo, fminf(ta, tb));
        ihi = fminf(ihi, fmaxf(ta, tb));
    } else if (cy < XLO || cy > XHI) {
        ihi = ilo - 1.0f;
    }

    int ib = s_begin, ie = s_begin;
    if (ihi >= ilo) {
        ib = max(s_begin, (int)ceilf ((ilo - T0) / DT - 0.5f));
        ie = min(s_end,   (int)floorf((ihi - T0) / DT - 0.5f) + 1);
        if (ie < ib) { ib = s_begin; ie = s_begin; }
    }

    const float fxs = gx * DT;
    const float fys = gy * DT;
    const float fx0 = fmaf(gx, T0 + 0.5f * DT, cx);
    const float fy0 = fmaf(gy, T0 + 0.5f * DT, cy);

    int acc[NBATCH];
#pragma unroll
    for (int b = 0; b < NBATCH; ++b) acc[b] = 0;

    int s = s_begin + soff;          // this thread's samples: step 4

    // ---------------- border loop 1: s < ib --------------------------------
    for (; s < ib; s += 4) {
        const float sf = (float)s;
        const float fx = fmaf(fxs, sf, fx0);
        const float fy = fmaf(fys, sf, fy0);
        const float x0f = floorf(fx), y0f = floorf(fy);
        const float wx = fx - x0f, wy = fy - y0f;
        const int ix = (int)x0f, iy = (int)y0f;
        const float ax = 1.0f - wx, ay = 1.0f - wy;
        const bool vx0 = (unsigned)ix       < (unsigned)NPIX;
        const bool vx1 = (unsigned)(ix + 1) < (unsigned)NPIX;
        const bool vy0 = (unsigned)iy       < (unsigned)NPIX;
        const bool vy1 = (unsigned)(iy + 1) < (unsigned)NPIX;
        float w00 = (vx0 && vy0) ? ax * ay : 0.0f;
        float w01 = (vx1 && vy0) ? wx * ay : 0.0f;
        float w10 = (vx0 && vy1) ? ax * wy : 0.0f;
        float w11 = (vx1 && vy1) ? wx * wy : 0.0f;
        const bool xneg = (ix < 0);
        float s00 = xneg ? w01 : w00, s01 = xneg ? 0.0f : w01;
        float s10 = xneg ? w11 : w10, s11 = xneg ? 0.0f : w11;
        const bool yneg = (iy < 0);
        const float t00 = yneg ? s10 : s00, t10 = yneg ? 0.0f : s10;
        const float t01 = yneg ? s11 : s01, t11 = yneg ? 0.0f : s11;
        const int px = min(max(ix, 0), NPIX - 1);
        const int py = min(max(iy, 0), NPIX - 1);
        acc_quad_u4(pk[(py << 9) + px],
                    pack_w4d(t00, t01, t10, t11, dither_of(sf)), acc);
    }

    // ---- interior: s < ie, move-free unroll-2 pipeline --------------------
    if (s < ie) {
        const int n = (ie - s + 3) >> 2;        // # interior samples
        const float fxs8 = 8.0f * fxs, fys8 = 8.0f * fys;
        const float sf = (float)s;
        // slot A = logical sample 0
        float fxa = fmaf(fxs, sf, fx0), fya = fmaf(fys, sf, fy0);
        float dA = dither_of(sf);
        float xfa = floorf(fxa), yfa = floorf(fya);
        float wxa = fxa - xfa, wya = fya - yfa;
        int4 qa = pk[(int)fmaf(yfa, 512.0f, xfa)];
        if (n == 1) {
            consume(qa, wxa, wya, dA, acc);
        } else {
            // slot B = logical sample 1
            const float sfb = sf + 4.0f;
            float fxb = fmaf(fxs, sfb, fx0), fyb = fmaf(fys, sfb, fy0);
            float dB = dither_of(sfb);
            float xfb = floorf(fxb), yfb = floorf(fyb);
            float wxb = fxb - xfb, wyb = fyb - yfb;
            int4 qb = pk[(int)fmaf(yfb, 512.0f, xfb)];
            int k = 2;
            for (; k + 1 < n; k += 2) {
                consume(qa, wxa, wya, dA, acc);
                load_slot(pk, fxs8, fys8, fxa, fya, dA, qa, wxa, wya);
                consume(qb, wxb, wyb, dB, acc);
                load_slot(pk, fxs8, fys8, fxb, fyb, dB, qb, wxb, wyb);
            }
            if (k < n) {            // k == n-1: one tail sample via slot A
                consume(qa, wxa, wya, dA, acc);
                load_slot(pk, fxs8, fys8, fxa, fya, dA, qa, wxa, wya);
                consume(qb, wxb, wyb, dB, acc);
                consume(qa, wxa, wya, dA, acc);
            } else {                // k == n
                consume(qa, wxa, wya, dA, acc);
                consume(qb, wxb, wyb, dB, acc);
            }
        }
        s += n << 2;
    }

    // ---------------- border loop 2: s < s_end -----------------------------
    for (; s < s_end; s += 4) {
        const float sf = (float)s;
        const float fx = fmaf(fxs, sf, fx0);
        const float fy = fmaf(fys, sf, fy0);
        const float x0f = floorf(fx), y0f = floorf(fy);
        const float wx = fx - x0f, wy = fy - y0f;
        const int ix = (int)x0f, iy = (int)y0f;
        const float ax = 1.0f - wx, ay = 1.0f - wy;
        const bool vx0 = (unsigned)ix       < (unsigned)NPIX;
        const bool vx1 = (unsigned)(ix + 1) < (unsigned)NPIX;
        const bool vy0 = (unsigned)iy       < (unsigned)NPIX;
        const bool vy1 = (unsigned)(iy + 1) < (unsigned)NPIX;
        float w00 = (vx0 && vy0) ? ax * ay : 0.0f;
        float w01 = (vx1 && vy0) ? wx * ay : 0.0f;
        float w10 = (vx0 && vy1) ? ax * wy : 0.0f;
        float w11 = (vx1 && vy1) ? wx * wy : 0.0f;
        const bool xneg = (ix < 0);
        float s00 = xneg ? w01 : w00, s01 = xneg ? 0.0f : w01;
        float s10 = xneg ? w11 : w10, s11 = xneg ? 0.0f : w11;
        const bool yneg = (iy < 0);
        const float t00 = yneg ? s10 : s00, t10 = yneg ? 0.0f : s10;
        const float t01 = yneg ? s11 : s01, t11 = yneg ? 0.0f : s11;
        const int px = min(max(ix, 0), NPIX - 1);
        const int py = min(max(iy, 0), NPIX - 1);
        acc_quad_u4(pk[(py << 9) + px],
                    pack_w4d(t00, t01, t10, t11, dither_of(sf)), acc);
    }

    // ---- reduce the 4 soff partials, scale, store -------------------------
#pragma unroll
    for (int b = 0; b < NBATCH; ++b) {
        int a = acc[b];
        a += __shfl_xor(a, 16, 64);
        a += __shfl_xor(a, 32, 64);
        acc[b] = a;
    }

    if (soff == 0) {
        const float SCALE = DT * (1.0f / (15.0f * 15.0f));
#pragma unroll
        for (int b = 0; b < NBATCH; ++b)
            out[((size_t)b * NVIEW + v) * NDET + d] = (float)acc[b] * SCALE;
    }
}

// ---------------------------------------------------------------------------
// Fallback (original layout, fp32 scalar loads) — only if ws too small.
// ---------------------------------------------------------------------------
__global__ __launch_bounds__(256) void projector_kernel_fallback(
    const float* __restrict__ image, const float* __restrict__ views,
    float* __restrict__ out)
{
    const int d = blockIdx.x * blockDim.x + threadIdx.x;
    const int v = blockIdx.y;
    if (d >= NDET) return;

    const float PIX = 0.7433f, ISO = 595.0f;
    const float SDD_ = 595.0f + 490.6f;
    const float DGAM = 1.2858f / SDD_;
    const float FOV  = 512.0f * 0.7433f * 0.70710678f;
    const float T0   = ISO - FOV;
    const float DT   = 2.0f * FOV / (float)NSAMP;

    const float beta  = views[v];
    const float gamma = ((float)d - 0.5f * (float)(NDET - 1)) * DGAM;
    const float sx = ISO * cosf(beta), sy = ISO * sinf(beta);
    const float ang = beta + 3.14159265358979f + gamma;
    const float gx = cosf(ang) / PIX, gy = sinf(ang) / PIX;
    const float cx = sx / PIX + 0.5f * (float)(NPIX - 1);
    const float cy = sy / PIX + 0.5f * (float)(NPIX - 1);

    float acc[NBATCH];
#pragma unroll
    for (int b = 0; b < NBATCH; ++b) acc[b] = 0.0f;

    for (int s = 0; s < NSAMP; ++s) {
        const float t  = fmaf((float)s + 0.5f, DT, T0);
        const float fx = fmaf(gx, t, cx);
        const float fy = fmaf(gy, t, cy);
        const float x0f = floorf(fx), y0f = floorf(fy);
        const float wx = fx - x0f, wy = fy - y0f;
        const int ix = (int)x0f, iy = (int)y0f;
        const float ax = 1.0f - wx, ay = 1.0f - wy;
        const bool vx0 = (unsigned)ix < (unsigned)NPIX;
        const bool vx1 = (unsigned)(ix + 1) < (unsigned)NPIX;
        const bool vy0 = (unsigned)iy < (unsigned)NPIX;
        const bool vy1 = (unsigned)(iy + 1) < (unsigned)NPIX;
        const float w00 = (vx0 && vy0) ? ax * ay : 0.0f;
        const float w01 = (vx1 && vy0) ? wx * ay : 0.0f;
        const float w10 = (vx0 && vy1) ? ax * wy : 0.0f;
        const float w11 = (vx1 && vy1) ? wx * wy : 0.0f;
        const int xc0 = min(max(ix, 0), NPIX - 1);
        const int xc1 = min(max(ix + 1, 0), NPIX - 1);
        const int yc0 = min(max(iy, 0), NPIX - 1);
        const int yc1 = min(max(iy + 1, 0), NPIX - 1);
        const int i00 = (yc0 << 9) + xc0, i01 = (yc0 << 9) + xc1;
        const int i10 = (yc1 << 9) + xc0, i11 = (yc1 << 9) + xc1;
#pragma unroll
        for (int b = 0; b < NBATCH; ++b) {
            const float* img = image + (size_t)b * (NPIX * NPIX);
            acc[b] = fmaf(w00, img[i00], fmaf(w01, img[i01],
                     fmaf(w10, img[i10], fmaf(w11, img[i11], acc[b]))));
        }
    }
#pragma unroll
    for (int b = 0; b < NBATCH; ++b)
        out[((size_t)b * NVIEW + v) * NDET + d] = acc[b] * DT;
}

extern "C" void kernel_launch(void* const* d_in, const int* in_sizes, int n_in,
                              void* d_out, int out_size, void* d_ws, size_t ws_size,
                              hipStream_t stream) {
    const float* image = (const float*)d_in[0];
    const float* views = (const float*)d_in[1];
    float* out = (float*)d_out;

    const size_t packed_bytes = (size_t)NPIX * NPIX * sizeof(int4);
    if (ws_size >= packed_bytes && d_ws != nullptr) {
        int4* packed = (int4*)d_ws;
        repack_kernel<<<dim3((NPIX * NPIX) / 256), dim3(256), 0, stream>>>(image, packed);
        projector_kernel<<<dim3(NDET / 64, NVIEW), dim3(256), 0, stream>>>(
            packed, views, out);
    } else {
        projector_kernel_fallback<<<dim3(NDET / 256, NVIEW), dim3(256), 0, stream>>>(image, views, out);
    }
}

// Round 16
// 206.464 us; speedup vs baseline: 57.6780x; 1.0241x over previous
//
#include <hip/hip_runtime.h>

#define NPIX   512
#define NDET   768
#define NSAMP  768
#define NVIEW  360
#define NBATCH 8

typedef float v2f __attribute__((ext_vector_type(2)));

// u4 dot8: acc += sum_k nib_k(a)*nib_k(b).  Builtin gated in DEVICE pass only
// (R7 lesson: host-pass __has_builtin is false for amdgcn builtins).
__device__ __forceinline__ int udot8(int a, int b, int acc) {
#if defined(__HIP_DEVICE_COMPILE__) && defined(__has_builtin)
#if __has_builtin(__builtin_amdgcn_udot8)
    return (int)__builtin_amdgcn_udot8((unsigned)a, (unsigned)b, (unsigned)acc, false);
#define UDOT8_DONE 1
#endif
#endif
#ifndef UDOT8_DONE
#pragma unroll
    for (int k = 0; k < 8; ++k)
        acc += ((a >> (4 * k)) & 15) * ((b >> (4 * k)) & 15);
    return acc;
#endif
}

// pack 4 floats (each in [0,16)) into 4 bytes.
// R15 lesson: v_cvt_pk_u8_f32 ROUNDS-to-nearest -> +0.5 LSB weight BIAS that
// accumulates over ~550 samples into +25 absmax. Plain (int) casts emit
// v_cvt_u32_f32 which TRUNCATES (= floor for args >= 0) — verified R14
// (absmax 3.0). Do not "optimize" this with the pk builtin.
__device__ __forceinline__ int cvt4_u8(float f0, float f1, float f2, float f3) {
    return ((int)f0) | ((int)f1 << 8) | ((int)f2 << 16) | ((int)f3 << 24);
}

__device__ __forceinline__ float fracf(float x) { return x - floorf(x); }

// ---------------------------------------------------------------------------
// Repack image [8,512,512] fp32 -> u4 quad-pack, NIBBLE-INTERLEAVED batches:
//   pixel (y,x), dword d (d=0..3) = batches {2d (even nibbles), 2d+1 (odd)}:
//     nibble 2c   = round(15*v[2d  ]) at corner c
//     nibble 2c+1 = round(15*v[2d+1]) at corner c
//   corners c: 0=(x,y) 1=(x+1,y) 2=(x,y+1) 3=(x+1,y+1)   (clamped)
// ONE dwordx4 gather = all 4 bilinear corners x all 8 batches.
// Footprint 4 MB -> L2-resident (R4 lesson: 8 MB thrashes).
// ---------------------------------------------------------------------------
__global__ __launch_bounds__(256) void repack_kernel(
    const float* __restrict__ image,    // [8, 512, 512]
    int4* __restrict__ packed)          // [512*512]
{
    const int idx = blockIdx.x * blockDim.x + threadIdx.x;  // (y<<9)|x
    if (idx >= NPIX * NPIX) return;
    const int x  = idx & (NPIX - 1);
    const int y  = idx >> 9;
    const int x1 = min(x + 1, NPIX - 1);
    const int y1 = min(y + 1, NPIX - 1);
    const int c0 = (y << 9) + x, c1 = (y << 9) + x1;
    const int c2 = (y1 << 9) + x, c3 = (y1 << 9) + x1;
    int w[4];
#pragma unroll
    for (int d = 0; d < 4; ++d) {
        const float* imgA = image + (size_t)(2 * d)     * (NPIX * NPIX);
        const float* imgB = image + (size_t)(2 * d + 1) * (NPIX * NPIX);
        const int a0 = (int)(imgA[c0] * 15.0f + 0.5f);
        const int a1 = (int)(imgA[c1] * 15.0f + 0.5f);
        const int a2 = (int)(imgA[c2] * 15.0f + 0.5f);
        const int a3 = (int)(imgA[c3] * 15.0f + 0.5f);
        const int b0 = (int)(imgB[c0] * 15.0f + 0.5f);
        const int b1 = (int)(imgB[c1] * 15.0f + 0.5f);
        const int b2 = (int)(imgB[c2] * 15.0f + 0.5f);
        const int b3 = (int)(imgB[c3] * 15.0f + 0.5f);
        w[d] = a0 | (b0 << 4) | (a1 << 8)  | (b1 << 12)
             | (a2 << 16) | (b2 << 20) | (a3 << 24) | (b3 << 28);
    }
    packed[idx] = make_int4(w[0], w[1], w[2], w[3]);
}

// u4 DITHERED weights (8 udot8/sample).  wA: weight[c] in LOW nibble of
// byte c (even-batch nibbles); wA<<4 hits odd-batch nibbles.
// floor(15*w + dither) with shared per-sample dither is UNBIASED for every w
// (R9 lesson: constant-w axis-aligned rays need it; R15 lesson: any constant
// rounding BIAS accumulates linearly over the ray — only zero-mean error ok).
__device__ __forceinline__ void acc_quad_u4(const int4 q, const int wA,
                                            int acc[NBATCH]) {
    const int wB = wA << 4;
    acc[0] = udot8(q.x, wA, acc[0]);
    acc[1] = udot8(q.x, wB, acc[1]);
    acc[2] = udot8(q.y, wA, acc[2]);
    acc[3] = udot8(q.y, wB, acc[3]);
    acc[4] = udot8(q.z, wA, acc[4]);
    acc[5] = udot8(q.z, wB, acc[5]);
    acc[6] = udot8(q.w, wA, acc[6]);
    acc[7] = udot8(q.w, wB, acc[7]);
}

// scalar consume (borders / interior tails)
__device__ __forceinline__ void consume(const int4 q, float wx, float wy,
                                        float dith, int acc[NBATCH]) {
    const float ax   = 1.0f - wx;
    const float ay15 = fmaf(wy, -15.0f, 15.0f);
    const float wy15 = wy * 15.0f;
    acc_quad_u4(q, cvt4_u8(fmaf(ax, ay15, dith), fmaf(wx, ay15, dith),
                           fmaf(ax, wy15, dith), fmaf(wx, wy15, dith)), acc);
}

__device__ __forceinline__ int pack_w4d(float w00, float w01, float w10,
                                        float w11, float dith) {
    return cvt4_u8(fmaf(w00, 15.0f, dith), fmaf(w01, 15.0f, dith),
                   fmaf(w10, 15.0f, dith), fmaf(w11, 15.0f, dith));
}

__device__ __forceinline__ float dither_of(float sf) {
    return fracf(sf * 0.61803398875f);
}

// ---------------------------------------------------------------------------
// Main projector. Wave = 16 detectors x 4 sample-offsets (R6 patch locality).
// Per sample: ONE dwordx4 gather + 8 v_dot8 (dithered u4 weights).
// R16: interior processes slot-pair (A,B) with PACKED f32 math (v_pk_fma_f32);
// conversion via truncating (int) casts (R15 lesson). Address clamp (&0x3FFFF)
// keeps the final dead prefetch in-bounds so the loop body is branch-free.
// ---------------------------------------------------------------------------
__global__ __launch_bounds__(256) void projector_kernel(
    const int4* __restrict__ pk,        // [512*512] u4 quad-pack interleaved
    const float* __restrict__ views,    // [360]
    float* __restrict__ out)            // [8, 360, 768]
{
    const int lane    = threadIdx.x & 63;
    const int wave    = threadIdx.x >> 6;
    const int detlane = lane & 15;
    const int soff    = lane >> 4;
    const int d = blockIdx.x * 64 + wave * 16 + detlane;
    const int v = blockIdx.y;

    const float PIX   = 0.7433f;
    const float ISO   = 595.0f;
    const float SDD_  = 595.0f + 490.6f;
    const float DGAM  = 1.2858f / SDD_;
    const float FOV   = 512.0f * 0.7433f * 0.70710678f;
    const float T0    = ISO - FOV;
    const float DT    = 2.0f * FOV / (float)NSAMP;

    const float beta  = views[v];
    const float gamma = ((float)d - 0.5f * (float)(NDET - 1)) * DGAM;
    const float sx = ISO * cosf(beta);
    const float sy = ISO * sinf(beta);
    const float ang = beta + 3.14159265358979f + gamma;
    const float gx = cosf(ang) / PIX;
    const float gy = sinf(ang) / PIX;
    const float cx = sx / PIX + 0.5f * (float)(NPIX - 1);
    const float cy = sy / PIX + 0.5f * (float)(NPIX - 1);

    // ---- clip sample range to image support (contrib 0 outside (-1,512)) --
    const float PLO = -1.0f, PHI = 512.0f;
    float lo = T0 + 0.5f * DT;
    float hi = T0 + ((float)NSAMP - 0.5f) * DT;
    if (fabsf(gx) > 1e-8f) {
        float ta = (PLO - cx) / gx, tb = (PHI - cx) / gx;
        lo = fmaxf(lo, fminf(ta, tb));
        hi = fminf(hi, fmaxf(ta, tb));
    } else if (cx < PLO || cx > PHI) {
        hi = lo - 1.0f;
    }
    if (fabsf(gy) > 1e-8f) {
        float ta = (PLO - cy) / gy, tb = (PHI - cy) / gy;
        lo = fmaxf(lo, fminf(ta, tb));
        hi = fminf(hi, fmaxf(ta, tb));
    } else if (cy < PLO || cy > PHI) {
        hi = lo - 1.0f;
    }

    int s_begin = 0, s_end = 0;
    if (hi >= lo) {
        s_begin = max(0, (int)floorf((lo - T0) / DT - 0.5f));
        s_end   = min(NSAMP, (int)ceilf((hi - T0) / DT - 0.5f) + 1);
    }

    // ---- interior range: strictly inside [0.01, 510.99]^2 (no clamping) ---
    const float XLO = 0.01f, XHI = 510.99f;
    float ilo = lo, ihi = hi;
    if (fabsf(gx) > 1e-8f) {
        float ta = (XLO - cx) / gx, tb = (XHI - cx) / gx;
        ilo = fmaxf(ilo, fminf(ta, tb));
        ihi = fminf(ihi, fmaxf(ta, tb));
    } else if (cx < XLO || cx > XHI) {
        ihi = ilo - 1.0f;
    }
    if (fabsf(gy) > 1e-8f) {
        float ta = (XLO - cy) / gy, tb = (XHI - cy) / gy;
        ilo = fmaxf(ilo, fminf(ta, tb));
        ihi = fminf(ihi, fmaxf(ta, tb));
    } else if (cy < XLO || cy > XHI) {
        ihi = ilo - 1.0f;
    }

    int ib = s_begin, ie = s_begin;
    if (ihi >= ilo) {
        ib = max(s_begin, (int)ceilf ((ilo - T0) / DT - 0.5f));
        ie = min(s_end,   (int)floorf((ihi - T0) / DT - 0.5f) + 1);
        if (ie < ib) { ib = s_begin; ie = s_begin; }
    }

    const float fxs = gx * DT;
    const float fys = gy * DT;
    const float fx0 = fmaf(gx, T0 + 0.5f * DT, cx);
    const float fy0 = fmaf(gy, T0 + 0.5f * DT, cy);

    int acc[NBATCH];
#pragma unroll
    for (int b = 0; b < NBATCH; ++b) acc[b] = 0;

    int s = s_begin + soff;          // this thread's samples: step 4

    // ---------------- border loop 1: s < ib --------------------------------
    for (; s < ib; s += 4) {
        const float sf = (float)s;
        const float fx = fmaf(fxs, sf, fx0);
        const float fy = fmaf(fys, sf, fy0);
        const float x0f = floorf(fx), y0f = floorf(fy);
        const float wx = fx - x0f, wy = fy - y0f;
        const int ix = (int)x0f, iy = (int)y0f;
        const float ax = 1.0f - wx, ay = 1.0f - wy;
        const bool vx0 = (unsigned)ix       < (unsigned)NPIX;
        const bool vx1 = (unsigned)(ix + 1) < (unsigned)NPIX;
        const bool vy0 = (unsigned)iy       < (unsigned)NPIX;
        const bool vy1 = (unsigned)(iy + 1) < (unsigned)NPIX;
        float w00 = (vx0 && vy0) ? ax * ay : 0.0f;
        float w01 = (vx1 && vy0) ? wx * ay : 0.0f;
        float w10 = (vx0 && vy1) ? ax * wy : 0.0f;
        float w11 = (vx1 && vy1) ? wx * wy : 0.0f;
        const bool xneg = (ix < 0);
        float s00 = xneg ? w01 : w00, s01 = xneg ? 0.0f : w01;
        float s10 = xneg ? w11 : w10, s11 = xneg ? 0.0f : w11;
        const bool yneg = (iy < 0);
        const float t00 = yneg ? s10 : s00, t10 = yneg ? 0.0f : s10;
        const float t01 = yneg ? s11 : s01, t11 = yneg ? 0.0f : s11;
        const int px = min(max(ix, 0), NPIX - 1);
        const int py = min(max(iy, 0), NPIX - 1);
        acc_quad_u4(pk[(py << 9) + px],
                    pack_w4d(t00, t01, t10, t11, dither_of(sf)), acc);
    }

    // ---- interior: s < ie, packed slot-pair pipeline ----------------------
    if (s < ie) {
        const int n = (ie - s + 3) >> 2;        // # interior samples
        const float sf = (float)s;
        if (n == 1) {
            const float fx = fmaf(fxs, sf, fx0), fy = fmaf(fys, sf, fy0);
            const float xf = floorf(fx), yf = floorf(fy);
            consume(pk[(int)fmaf(yf, 512.0f, xf)], fx - xf, fy - yf,
                    dither_of(sf), acc);
        } else {
            const int pairs = n >> 1;
            v2f fxs8; fxs8.x = 8.0f * fxs; fxs8.y = 8.0f * fxs;
            v2f fys8; fys8.x = 8.0f * fys; fys8.y = 8.0f * fys;
            v2f dst8; dst8.x = 0.94427191f; dst8.y = 0.94427191f;  // frac(8φ)
            v2f fx2;  fx2.x = fmaf(fxs, sf, fx0);  fx2.y = fmaf(fxs, sf + 4.0f, fx0);
            v2f fy2;  fy2.x = fmaf(fys, sf, fy0);  fy2.y = fmaf(fys, sf + 4.0f, fy0);
            v2f d2;   d2.x  = dither_of(sf);       d2.y  = dither_of(sf + 4.0f);
            float xfa = floorf(fx2.x), yfa = floorf(fy2.x);
            float xfb = floorf(fx2.y), yfb = floorf(fy2.y);
            v2f wx2;  wx2.x = fx2.x - xfa;  wx2.y = fx2.y - xfb;
            v2f wy2;  wy2.x = fy2.x - yfa;  wy2.y = fy2.y - yfb;
            int4 qa = pk[(int)fmaf(yfa, 512.0f, xfa)];
            int4 qb = pk[(int)fmaf(yfb, 512.0f, xfb)];
            for (int k = 0; k < pairs; ++k) {
                // packed weight math for both slots (v_pk_fma_f32)
                const v2f ax2  = 1.0f - wx2;
                const v2f ay15 = wy2 * -15.0f + 15.0f;
                const v2f wy15 = wy2 * 15.0f;
                const v2f u0 = ax2 * ay15 + d2;
                const v2f u1 = wx2 * ay15 + d2;
                const v2f u2 = ax2 * wy15 + d2;
                const v2f u3 = wx2 * wy15 + d2;
                acc_quad_u4(qa, cvt4_u8(u0.x, u1.x, u2.x, u3.x), acc);
                acc_quad_u4(qb, cvt4_u8(u0.y, u1.y, u2.y, u3.y), acc);
                // advance both slots by 8 s-units; reload (addr clamped so the
                // final iteration's dead prefetch stays in-bounds)
                fx2 += fxs8; fy2 += fys8;
                v2f t2 = d2 + dst8;
                v2f nd; nd.x = t2.x - floorf(t2.x); nd.y = t2.y - floorf(t2.y);
                d2 = nd;
                xfa = floorf(fx2.x); yfa = floorf(fy2.x);
                xfb = floorf(fx2.y); yfb = floorf(fy2.y);
                wx2.x = fx2.x - xfa; wx2.y = fx2.y - xfb;
                wy2.x = fy2.x - yfa; wy2.y = fy2.y - yfb;
                qa = pk[((int)fmaf(yfa, 512.0f, xfa)) & 0x3FFFF];
                qb = pk[((int)fmaf(yfb, 512.0f, xfb)) & 0x3FFFF];
            }
            if (n & 1) {
                // tail sample s+4*(n-1): slot A sits there after `pairs`
                // advances (s + 8*pairs == s + 4*(n-1)); genuinely interior,
                // so the clamped reload address was exact.
                consume(qa, wx2.x, wy2.x, d2.x, acc);
            }
        }
        s += n << 2;
    }

    // ---------------- border loop 2: s < s_end -----------------------------
    for (; s < s_end; s += 4) {
        const float sf = (float)s;
        const float fx = fmaf(fxs, sf, fx0);
        const float fy = fmaf(fys, sf, fy0);
        const float x0f = floorf(fx), y0f = floorf(fy);
        const float wx = fx - x0f, wy = fy - y0f;
        const int ix = (int)x0f, iy = (int)y0f;
        const float ax = 1.0f - wx, ay = 1.0f - wy;
        const bool vx0 = (unsigned)ix       < (unsigned)NPIX;
        const bool vx1 = (unsigned)(ix + 1) < (unsigned)NPIX;
        const bool vy0 = (unsigned)iy       < (unsigned)NPIX;
        const bool vy1 = (unsigned)(iy + 1) < (unsigned)NPIX;
        float w00 = (vx0 && vy0) ? ax * ay : 0.0f;
        float w01 = (vx1 && vy0) ? wx * ay : 0.0f;
        float w10 = (vx0 && vy1) ? ax * wy : 0.0f;
        float w11 = (vx1 && vy1) ? wx * wy : 0.0f;
        const bool xneg = (ix < 0);
        float s00 = xneg ? w01 : w00, s01 = xneg ? 0.0f : w01;
        float s10 = xneg ? w11 : w10, s11 = xneg ? 0.0f : w11;
        const bool yneg = (iy < 0);
        const float t00 = yneg ? s10 : s00, t10 = yneg ? 0.0f : s10;
        const float t01 = yneg ? s11 : s01, t11 = yneg ? 0.0f : s11;
        const int px = min(max(ix, 0), NPIX - 1);
        const int py = min(max(iy, 0), NPIX - 1);
        acc_quad_u4(pk[(py << 9) + px],
                    pack_w4d(t00, t01, t10, t11, dither_of(sf)), acc);
    }

    // ---- reduce the 4 soff partials, scale, store -------------------------
#pragma unroll
    for (int b = 0; b < NBATCH; ++b) {
        int a = acc[b];
        a += __shfl_xor(a, 16, 64);
        a += __shfl_xor(a, 32, 64);
        acc[b] = a;
    }

    if (soff == 0) {
        const float SCALE = DT * (1.0f / (15.0f * 15.0f));
#pragma unroll
        for (int b = 0; b < NBATCH; ++b)
            out[((size_t)b * NVIEW + v) * NDET + d] = (float)acc[b] * SCALE;
    }
}

// ---------------------------------------------------------------------------
// Fallback (original layout, fp32 scalar loads) — only if ws too small.
// ---------------------------------------------------------------------------
__global__ __launch_bounds__(256) void projector_kernel_fallback(
    const float* __restrict__ image, const float* __restrict__ views,
    float* __restrict__ out)
{
    const int d = blockIdx.x * blockDim.x + threadIdx.x;
    const int v = blockIdx.y;
    if (d >= NDET) return;

    const float PIX = 0.7433f, ISO = 595.0f;
    const float SDD_ = 595.0f + 490.6f;
    const float DGAM = 1.2858f / SDD_;
    const float FOV  = 512.0f * 0.7433f * 0.70710678f;
    const float T0   = ISO - FOV;
    const float DT   = 2.0f * FOV / (float)NSAMP;

    const float beta  = views[v];
    const float gamma = ((float)d - 0.5f * (float)(NDET - 1)) * DGAM;
    const float sx = ISO * cosf(beta), sy = ISO * sinf(beta);
    const float ang = beta + 3.14159265358979f + gamma;
    const float gx = cosf(ang) / PIX, gy = sinf(ang) / PIX;
    const float cx = sx / PIX + 0.5f * (float)(NPIX - 1);
    const float cy = sy / PIX + 0.5f * (float)(NPIX - 1);

    float acc[NBATCH];
#pragma unroll
    for (int b = 0; b < NBATCH; ++b) acc[b] = 0.0f;

    for (int s = 0; s < NSAMP; ++s) {
        const float t  = fmaf((float)s + 0.5f, DT, T0);
        const float fx = fmaf(gx, t, cx);
        const float fy = fmaf(gy, t, cy);
        const float x0f = floorf(fx), y0f = floorf(fy);
        const float wx = fx - x0f, wy = fy - y0f;
        const int ix = (int)x0f, iy = (int)y0f;
        const float ax = 1.0f - wx, ay = 1.0f - wy;
        const bool vx0 = (unsigned)ix < (unsigned)NPIX;
        const bool vx1 = (unsigned)(ix + 1) < (unsigned)NPIX;
        const bool vy0 = (unsigned)iy < (unsigned)NPIX;
        const bool vy1 = (unsigned)(iy + 1) < (unsigned)NPIX;
        const float w00 = (vx0 && vy0) ? ax * ay : 0.0f;
        const float w01 = (vx1 && vy0) ? wx * ay : 0.0f;
        const float w10 = (vx0 && vy1) ? ax * wy : 0.0f;
        const float w11 = (vx1 && vy1) ? wx * wy : 0.0f;
        const int xc0 = min(max(ix, 0), NPIX - 1);
        const int xc1 = min(max(ix + 1, 0), NPIX - 1);
        const int yc0 = min(max(iy, 0), NPIX - 1);
        const int yc1 = min(max(iy + 1, 0), NPIX - 1);
        const int i00 = (yc0 << 9) + xc0, i01 = (yc0 << 9) + xc1;
        const int i10 = (yc1 << 9) + xc0, i11 = (yc1 << 9) + xc1;
#pragma unroll
        for (int b = 0; b < NBATCH; ++b) {
            const float* img = image + (size_t)b * (NPIX * NPIX);
            acc[b] = fmaf(w00, img[i00], fmaf(w01, img[i01],
                     fmaf(w10, img[i10], fmaf(w11, img[i11], acc[b]))));
        }
    }
#pragma unroll
    for (int b = 0; b < NBATCH; ++b)
        out[((size_t)b * NVIEW + v) * NDET + d] = acc[b] * DT;
}

extern "C" void kernel_launch(void* const* d_in, const int* in_sizes, int n_in,
                              void* d_out, int out_size, void* d_ws, size_t ws_size,
                              hipStream_t stream) {
    const float* image = (const float*)d_in[0];
    const float* views = (const float*)d_in[1];
    float* out = (float*)d_out;

    const size_t packed_bytes = (size_t)NPIX * NPIX * sizeof(int4);
    if (ws_size >= packed_bytes && d_ws != nullptr) {
        int4* packed = (int4*)d_ws;
        repack_kernel<<<dim3((NPIX * NPIX) / 256), dim3(256), 0, stream>>>(image, packed);
        projector_kernel<<<dim3(NDET / 64, NVIEW), dim3(256), 0, stream>>>(
            packed, views, out);
    } else {
        projector_kernel_fallback<<<dim3(NDET / 256, NVIEW), dim3(256), 0, stream>>>(image, views, out);
    }
}